// Round 12
// baseline (350.851 us; speedup 1.0000x reference)
//
#include <hip/hip_runtime.h>
#include <math.h>

#define B_   2
#define T_   1024
#define C_   768
#define DH_  64
#define NH_  12
#define HT_  48

typedef short bf16x8 __attribute__((ext_vector_type(8)));
typedef float f32x4 __attribute__((ext_vector_type(4)));

__device__ __forceinline__ float wave_sum(float v) {
#pragma unroll
    for (int off = 32; off; off >>= 1) v += __shfl_xor(v, off, 64);
    return v;
}
__device__ __forceinline__ unsigned short rne_bf16(float f) {
    unsigned u = __float_as_uint(f);
    return (unsigned short)((u + 0x7FFFu + ((u >> 16) & 1u)) >> 16);
}
__device__ __forceinline__ float bf2f(unsigned short u) {
    return __uint_as_float((unsigned)u << 16);
}

#define LOG2E 1.4426950408889634f
#define KBIAS 32.0f

// work tables: 40 (tile,part) units per (b,h), heavy-first. chunk = 64 cols, part = 4 chunks.
__constant__ int c_tileTab[40] = {15,15,15,15, 14,14,14, 13,13,13, 12,12,12, 11,11,11,
                                  10,10, 9,9, 8,8, 7,7, 6, 5, 4, 3,
                                  14,10,6,2, 13,9,5,1, 12,8,4,0};
__constant__ int c_partTab[40] = { 0, 1, 2, 3,  0, 1, 2,  0, 1, 2,  0, 1, 2,  0, 1, 2,
                                   0, 1, 0,1, 0,1, 0,1, 0, 0, 0, 0,
                                   3, 2,1,0,  3,2,1,0,  3,2,1,0};

// ---------------------------------------------------------------- fused prep: wo_transpose + cvt + S/rope/wob
__global__ __launch_bounds__(256) void prep_all(
    const float* __restrict__ wA, const float* __restrict__ wb, const float* __restrict__ WOb,
    const float* __restrict__ A, const float* __restrict__ X,
    const float* __restrict__ Wq, const float* __restrict__ Wk,
    const float* __restrict__ fcw, const float* __restrict__ pw, const float* __restrict__ WO,
    float* __restrict__ S, float* __restrict__ rc, float* __restrict__ rs, float* __restrict__ wob,
    unsigned short* __restrict__ Ab, unsigned short* __restrict__ Xb,
    unsigned short* __restrict__ Wqb, unsigned short* __restrict__ Wkb,
    unsigned short* __restrict__ fcb, unsigned short* __restrict__ pwb,
    unsigned short* __restrict__ WOt) {
    __shared__ float tl[32][33];
    const int bid = blockIdx.x;
    if (bid < 2304) {               // WO transpose (4,768,768) -> WOt[d][n*768+c] bf16
        const int n = bid / 576, rem = bid % 576;
        const int d0 = (rem / 24) * 32, c0 = (rem % 24) * 32;
        const int tx = threadIdx.x & 31, ty = threadIdx.x >> 5;
#pragma unroll
        for (int p = 0; p < 4; p++)
            tl[ty + p * 8][tx] = WO[(size_t)n * 589824 + (size_t)(c0 + ty + p * 8) * 768 + d0 + tx];
        __syncthreads();
#pragma unroll
        for (int p = 0; p < 4; p++)
            WOt[(size_t)(d0 + ty + p * 8) * 3072 + n * 768 + c0 + tx] = rne_bf16(tl[tx][ty + p * 8]);
    } else if (bid < 8288) {        // f32 -> bf16 conversions, float4 granularity
        int i = (bid - 2304) * 256 + threadIdx.x;
        const float* s; unsigned short* d; int o;
        if (i < 393216)       { s = A;   d = Ab;  o = i; }
        else if (i < 786432)  { s = X;   d = Xb;  o = i - 393216; }
        else if (i < 1376256) { s = Wq;  d = Wqb; o = i - 786432; }
        else if (i < 1523712) { s = Wk;  d = Wkb; o = i - 1376256; }
        else if (i < 1527808) { s = fcw; d = fcb; o = i - 1523712; }
        else if (i < 1531904) { s = pw;  d = pwb; o = i - 1527808; }
        else return;
        float4 v = reinterpret_cast<const float4*>(s)[o];
        ushort4 u;
        u.x = rne_bf16(v.x); u.y = rne_bf16(v.y); u.z = rne_bf16(v.z); u.w = rne_bf16(v.w);
        reinterpret_cast<ushort4*>(d)[o] = u;
    } else {                        // S, rope tables, wob
        int i = (bid - 8288) * 256 + threadIdx.x;
        if (i < HT_ * 64 * 64) {
            int e = i & 63, d = (i >> 6) & 63, h = i >> 12;
            float v = wA[d * 64 + e] - wA[e * 64 + d];
            if (d == e) v += wb[h * 64 + d];
            S[i] = v;
        } else if (i < HT_ * 64 * 64 + T_ * 32) {
            int j = i - HT_ * 64 * 64;
            int t = j >> 5, f = j & 31;
            float invf = (float)(1.0 / pow(10000.0, (double)f / 32.0));
            float fr = (float)t * invf;
            rc[j] = cosf(fr);
            rs[j] = sinf(fr);
        } else if (i < HT_ * 64 * 64 + T_ * 32 + C_) {
            int d = i - (HT_ * 64 * 64 + T_ * 32);
            wob[d] = WOb[d] + WOb[C_ + d] + WOb[2 * C_ + d] + WOb[3 * C_ + d];
        }
    }
}

// ---------------------------------------------------------------- q-proj + k-proj in one grid (128x128 MFMA, K=768)
__global__ __launch_bounds__(256) void gemm_qk(
    const unsigned short* __restrict__ Aq, const unsigned short* __restrict__ Wqw,
    const float* __restrict__ bq, float* __restrict__ Cq,
    const unsigned short* __restrict__ Ak, const unsigned short* __restrict__ Wkw,
    const float* __restrict__ bk, float* __restrict__ Ck) {
    __shared__ unsigned short Asd[128][40];
    __shared__ unsigned short Bsd[128][40];
    int bx = blockIdx.x;
    const unsigned short *A, *W; const float* bias; float* C; int N;
    if (bx < 24) { A = Aq; W = Wqw; bias = bq; C = Cq; N = 3072; }
    else { bx -= 24; A = Ak; W = Wkw; bias = bk; C = Ck; N = 768; }
    const int K = 768;
    const int tid = threadIdx.x;
    const int wv = tid >> 6, lane = tid & 63;
    const int m0 = blockIdx.y * 128, n0 = bx * 128;
    const int wr = (wv >> 1) * 64, wc = (wv & 1) * 64;
    const int l15 = lane & 15, l4 = lane >> 4;
    const int srow = tid >> 2, soff = (tid & 3) * 8;
    f32x4 acc[4][4] = {};
    for (int k0 = 0; k0 < K; k0 += 32) {
        uint4 a0 = *reinterpret_cast<const uint4*>(A + (size_t)(m0 + srow) * K + k0 + soff);
        uint4 a1 = *reinterpret_cast<const uint4*>(A + (size_t)(m0 + srow + 64) * K + k0 + soff);
        uint4 b0 = *reinterpret_cast<const uint4*>(W + (size_t)(n0 + srow) * K + k0 + soff);
        uint4 b1 = *reinterpret_cast<const uint4*>(W + (size_t)(n0 + srow + 64) * K + k0 + soff);
        *reinterpret_cast<uint4*>(&Asd[srow][soff])      = a0;
        *reinterpret_cast<uint4*>(&Asd[srow + 64][soff]) = a1;
        *reinterpret_cast<uint4*>(&Bsd[srow][soff])      = b0;
        *reinterpret_cast<uint4*>(&Bsd[srow + 64][soff]) = b1;
        __syncthreads();
        bf16x8 af[4], bfr[4];
#pragma unroll
        for (int i = 0; i < 4; i++)
            af[i] = *reinterpret_cast<const bf16x8*>(&Asd[wr + i * 16 + l15][l4 * 8]);
#pragma unroll
        for (int j = 0; j < 4; j++)
            bfr[j] = *reinterpret_cast<const bf16x8*>(&Bsd[wc + j * 16 + l15][l4 * 8]);
#pragma unroll
        for (int i = 0; i < 4; i++)
#pragma unroll
            for (int j = 0; j < 4; j++)
                acc[i][j] = __builtin_amdgcn_mfma_f32_16x16x32_bf16(af[i], bfr[j], acc[i][j], 0, 0, 0);
        __syncthreads();
    }
#pragma unroll
    for (int i = 0; i < 4; i++)
#pragma unroll
        for (int j = 0; j < 4; j++) {
            int col = n0 + wc + j * 16 + l15;
            float bv = bias[col];
#pragma unroll
            for (int r = 0; r < 4; r++) {
                int row = m0 + wr + i * 16 + l4 * 4 + r;
                C[(size_t)row * N + col] = acc[i][j][r] + bv;
            }
        }
}

// ---------------------------------------------------------------- bf16 MFMA GEMM 64x64 tile (for WO, K=3072)
__global__ __launch_bounds__(256) void gemm_bf16_64(const unsigned short* __restrict__ A,
                                                    const unsigned short* __restrict__ W,
                                                    const float* __restrict__ bias,
                                                    float* __restrict__ C,
                                                    int M, int N, int K, float scl) {
    __shared__ unsigned short Asd[64][40];
    __shared__ unsigned short Bsd[64][40];
    const int tid = threadIdx.x;
    const int wv = tid >> 6, lane = tid & 63;
    const int m0 = blockIdx.y * 64, n0 = blockIdx.x * 64;
    const int l15 = lane & 15, l4 = lane >> 4;
    const int srow = tid >> 2, soff = (tid & 3) * 8;
    f32x4 acc[4] = {};
    for (int k0 = 0; k0 < K; k0 += 32) {
        uint4 a0 = *reinterpret_cast<const uint4*>(A + (size_t)(m0 + srow) * K + k0 + soff);
        uint4 b0 = *reinterpret_cast<const uint4*>(W + (size_t)(n0 + srow) * K + k0 + soff);
        *reinterpret_cast<uint4*>(&Asd[srow][soff]) = a0;
        *reinterpret_cast<uint4*>(&Bsd[srow][soff]) = b0;
        __syncthreads();
        bf16x8 af = *reinterpret_cast<const bf16x8*>(&Asd[wv * 16 + l15][l4 * 8]);
#pragma unroll
        for (int j = 0; j < 4; j++) {
            bf16x8 bfr = *reinterpret_cast<const bf16x8*>(&Bsd[j * 16 + l15][l4 * 8]);
            acc[j] = __builtin_amdgcn_mfma_f32_16x16x32_bf16(af, bfr, acc[j], 0, 0, 0);
        }
        __syncthreads();
    }
#pragma unroll
    for (int j = 0; j < 4; j++) {
        int col = n0 + j * 16 + l15;
        float bv = bias[col];
#pragma unroll
        for (int r = 0; r < 4; r++) {
            int row = m0 + wv * 16 + l4 * 4 + r;
            C[(size_t)row * N + col] = (acc[j][r] + bv) * scl;
        }
    }
}

// ---------------------------------------------------------------- q + k transforms in one grid
__global__ __launch_bounds__(256) void transform_qk(
    const float* __restrict__ qb, const float* __restrict__ kbv, const float* __restrict__ S,
    const float* __restrict__ rc, const float* __restrict__ rs,
    unsigned short* __restrict__ qhi, unsigned short* __restrict__ qlo,
    unsigned short* __restrict__ khi, unsigned short* __restrict__ klo) {
    const int tid = threadIdx.x, wv = tid >> 6, lane = tid & 63;
    const bool isQ = blockIdx.x < 1536;
    const int bidx = isQ ? blockIdx.x : blockIdx.x - 1536;
    const int h = bidx >> 5, blk = bidx & 31;
    const int hk = h % 12;
    __shared__ float Sl[4096];
    __shared__ float sh[4][64];
    const float4* Sg = reinterpret_cast<const float4*>(S + h * 4096);
#pragma unroll
    for (int i = 0; i < 4; i++)
        reinterpret_cast<float4*>(Sl)[tid + 256 * i] = Sg[tid + 256 * i];
    __syncthreads();
    unsigned short* ohi = isQ ? qhi : khi;
    unsigned short* olo = isQ ? qlo : klo;
    for (int it = 0; it < 16; ++it) {
        int r = (blk << 6) + (wv << 4) + it;   // 0..2047
        int b = r >> 10, t = r & 1023;
        float v;
        if (isQ) {
            v = qb[((((size_t)(b << 10) + t) * 48 + h) << 6) + lane];
            float ss = wave_sum(v * v);
            v *= 1.f / sqrtf(ss * (1.f / 64.f) + 1.1920928955078125e-07f);
        } else {
            v = kbv[((((size_t)(b << 10) + t) * 12 + hk) << 6) + lane];
        }
        sh[wv][lane] = v;
        float acc = v;
#pragma unroll 8
        for (int d = 0; d < 64; d++) acc = fmaf(sh[wv][d], Sl[(d << 6) + lane], acc);
        sh[wv][lane] = acc;
        int j = lane & 31;
        float x1 = sh[wv][2 * j], x2 = sh[wv][2 * j + 1];
        float ct = rc[t * 32 + j], st = rs[t * 32 + j];
        float o = (lane < 32) ? (x1 * ct - x2 * st) : (x1 * st + x2 * ct);
        if (isQ) o *= 0.125f * LOG2E;          // exp2 domain
        unsigned short oh = rne_bf16(o);
        unsigned short ol = rne_bf16(o - bf2f(oh));
        size_t oidx = ((((size_t)(b * 48 + h)) << 10) + t) * 64 + lane;
        ohi[oidx] = oh;
        olo[oidx] = ol;
    }
}

#define POPQ(qq)                                                                  \
    {                                                                             \
        bool tk = (qq[0] == hm);                                                  \
        qq[0]=tk?qq[1]:qq[0]; qq[1]=tk?qq[2]:qq[1]; qq[2]=tk?qq[3]:qq[2];         \
        qq[3]=tk?qq[4]:qq[3]; qq[4]=tk?qq[5]:qq[4]; qq[5]=tk?qq[6]:qq[5];         \
        qq[6]=tk?qq[7]:qq[6]; qq[7]=tk?qq[8]:qq[7]; qq[8]=tk?qq[9]:qq[8];         \
        qq[9]=tk?qq[10]:qq[9]; qq[10]=tk?qq[11]:qq[10]; qq[11]=tk?0u:qq[11];      \
    }

#define TOP12INS(pln, pk)                                                         \
    {                                                                             \
        unsigned _p = (pk);                                                       \
        _Pragma("unroll")                                                         \
        for (int jj = 0; jj < 12; jj++) {                                         \
            unsigned mx = pln[jj] > _p ? pln[jj] : _p;                            \
            _p = pln[jj] > _p ? _p : pln[jj];                                     \
            pln[jj] = mx;                                                         \
        }                                                                         \
    }

// ---------------------------------------------------------------- phase A: MFMA scores, exp2 domain, +KBIAS in acc
// r6-measured launch shape: ONE wave per 64-thread block, natural unit map
// (moderate occupancy keeps the concurrent k working set within L2; higher
// occupancy measured to thrash L2: FETCH 52->238->375MB r6/r8/r9).
__global__ __launch_bounds__(64, 3) void attn_scores(
    const unsigned short* __restrict__ qhi, const unsigned short* __restrict__ qlo,
    const unsigned short* __restrict__ khi, const unsigned short* __restrict__ klo,
    float* __restrict__ pZ, unsigned int* __restrict__ pP) {
    const int lane = threadIdx.x;
    const int bid = blockIdx.x;
    const int u = bid / 96, bh = bid % 96;
    const int tile = c_tileTab[u >> 1], part = c_partTab[u >> 1], half = u & 1;
    const int l15 = lane & 15, l4 = lane >> 4;
    const int t0 = (tile << 6) + (half << 5);
    const int c0 = part << 2;
    const int c1 = min(c0 + 4, tile + 1);
    const size_t base = ((size_t)bh) << 16;

    bf16x8 qh8[2][2], ql8[2][2];
#pragma unroll
    for (int ni = 0; ni < 2; ni++)
#pragma unroll
        for (int ks = 0; ks < 2; ks++) {
            size_t off = base + (size_t)(t0 + ni * 16 + l15) * 64 + ks * 32 + l4 * 8;
            qh8[ni][ks] = *reinterpret_cast<const bf16x8*>(qhi + off);
            ql8[ni][ks] = *reinterpret_cast<const bf16x8*>(qlo + off);
        }

    unsigned int pl[2][12];
#pragma unroll
    for (int ni = 0; ni < 2; ni++)
#pragma unroll
        for (int i = 0; i < 12; i++) pl[ni][i] = 0u;
    float Zp[2] = {0.f, 0.f};

    for (int cc = c0; cc < c1; ++cc) {
        f32x4 acc[4][2];
#pragma unroll
        for (int mi = 0; mi < 4; mi++)
#pragma unroll
            for (int ni = 0; ni < 2; ni++)
                acc[mi][ni] = (f32x4){KBIAS, KBIAS, KBIAS, KBIAS};
#pragma unroll
        for (int ks = 0; ks < 2; ks++) {
            bf16x8 kh8[4], kl8[4];
#pragma unroll
            for (int mi = 0; mi < 4; mi++) {
                size_t off = base + (size_t)((cc << 6) + mi * 16 + l15) * 64 + ks * 32 + l4 * 8;
                kh8[mi] = *reinterpret_cast<const bf16x8*>(khi + off);
                kl8[mi] = *reinterpret_cast<const bf16x8*>(klo + off);
            }
#pragma unroll
            for (int mi = 0; mi < 4; mi++)
#pragma unroll
                for (int ni = 0; ni < 2; ni++) {
                    acc[mi][ni] = __builtin_amdgcn_mfma_f32_16x16x32_bf16(kh8[mi], qh8[ni][ks], acc[mi][ni], 0, 0, 0);
                    acc[mi][ni] = __builtin_amdgcn_mfma_f32_16x16x32_bf16(kh8[mi], ql8[ni][ks], acc[mi][ni], 0, 0, 0);
                    acc[mi][ni] = __builtin_amdgcn_mfma_f32_16x16x32_bf16(kl8[mi], qh8[ni][ks], acc[mi][ni], 0, 0, 0);
                }
        }
        if (cc == tile) {   // diagonal chunk: causal mask
#pragma unroll
            for (int ni = 0; ni < 2; ni++) {
                const int tq = t0 + ni * 16 + l15;
#pragma unroll
                for (int mi = 0; mi < 4; mi++)
#pragma unroll
                    for (int r = 0; r < 4; r++) {
                        int kcol = (cc << 6) + mi * 16 + l4 * 4 + r;
                        float s = acc[mi][ni][r];
                        bool ok = kcol <= tq;
                        float e = exp2f(s);
                        Zp[ni] += ok ? e : 0.f;
                        unsigned pk = (__float_as_uint(s) & 0xFFFFFC00u) | (unsigned)(1023 - kcol);
                        pk = ok ? pk : 0u;
                        TOP12INS(pl[ni], pk);
                    }
            }
        } else {            // interior chunk: all valid
#pragma unroll
            for (int ni = 0; ni < 2; ni++) {
#pragma unroll
                for (int mi = 0; mi < 4; mi++)
#pragma unroll
                    for (int r = 0; r < 4; r++) {
                        int kcol = (cc << 6) + mi * 16 + l4 * 4 + r;
                        float s = acc[mi][ni][r];
                        Zp[ni] += exp2f(s);
                        unsigned pk = (__float_as_uint(s) & 0xFFFFFC00u) | (unsigned)(1023 - kcol);
                        TOP12INS(pl[ni], pk);
                    }
            }
        }
    }

    // in-wave 4-lane merge per qrow (single wave per block)
    __shared__ unsigned int lsh[64][2][12];
    __shared__ float zsh[64][2];
#pragma unroll
    for (int ni = 0; ni < 2; ni++) {
#pragma unroll
        for (int i = 0; i < 12; i++) lsh[lane][ni][i] = pl[ni][i];
        zsh[lane][ni] = Zp[ni];
    }
    __syncthreads();
    if (lane < 32) {
        const int ni = lane >> 4, c = lane & 15;
        unsigned int m0[12], m1[12], m2[12], m3[12];
#pragma unroll
        for (int i = 0; i < 12; i++) {
            m0[i] = lsh[c][ni][i];
            m1[i] = lsh[c + 16][ni][i];
            m2[i] = lsh[c + 32][ni][i];
            m3[i] = lsh[c + 48][ni][i];
        }
        float Z = zsh[c][ni] + zsh[c + 16][ni] + zsh[c + 32][ni] + zsh[c + 48][ni];
        unsigned int out[12];
#pragma unroll
        for (int rd = 0; rd < 12; rd++) {
            unsigned int ha = m0[0] > m1[0] ? m0[0] : m1[0];
            unsigned int hb2 = m2[0] > m3[0] ? m2[0] : m3[0];
            unsigned int hm = ha > hb2 ? ha : hb2;
            POPQ(m0); POPQ(m1); POPQ(m2); POPQ(m3);
            out[rd] = hm;
        }
        const size_t r = (((size_t)bh) << 10) + t0 + lane;
        pZ[r * 4 + part] = Z;
        unsigned int* pp = pP + r * 48 + part * 12;
        *reinterpret_cast<uint4*>(pp + 0) = make_uint4(out[0], out[1], out[2], out[3]);
        *reinterpret_cast<uint4*>(pp + 4) = make_uint4(out[4], out[5], out[6], out[7]);
        *reinterpret_cast<uint4*>(pp + 8) = make_uint4(out[8], out[9], out[10], out[11]);
    }
}

// ---------------------------------------------------------------- fused merge + marker-gather + fc + act + proj + sink
// 128-thread blocks (2 waves): LDS 17.4KB -> 9 blocks/CU (occupancy
// experiment vs r10's 4 blocks); launch_bounds(128,4) pins VGPR <= 128.
// lane: l15 = row, l4 = part-queue (merge) / k-chunk (gather).
__global__ __launch_bounds__(128, 4) void mlp_fused(
    const unsigned int* __restrict__ pP, const float* __restrict__ pZ,
    const float* __restrict__ sink_s, const float* __restrict__ kb,
    const unsigned short* __restrict__ fcw, const float* __restrict__ fcb,
    const unsigned short* __restrict__ pw, const float* __restrict__ pb,
    const float* __restrict__ vn, unsigned short* __restrict__ ctx) {
    const int tid = threadIdx.x, wv = tid >> 6, lane = tid & 63;
    const int l15 = lane & 15, l4 = lane >> 4;
    const int wid = blockIdx.x * 2 + wv;          // 0..6143
    const int r0 = wid << 4;
    const int bh = wid >> 6;
    const int h = bh % 48, b = bh / 48, hk = h % 12;
    const int tbase = r0 & 1023;
    const int tile = tbase >> 6;
    const int npart = (tile >> 2) + 1;            // wave-uniform
    __shared__ unsigned short hsd[2][16][272];

    // ---- inline part-merge: lane l4 owns queue (part) l4 of row l15 ----
    const int row = r0 + l15;
    unsigned int qq[12];
    {
        const bool val = l4 < npart;
        uint4 x0 = make_uint4(0,0,0,0), x1 = x0, x2 = x0;
        if (val) {
            const uint4* ip = reinterpret_cast<const uint4*>(pP + (size_t)row * 48 + l4 * 12);
            x0 = ip[0]; x1 = ip[1]; x2 = ip[2];
        }
        qq[0]=x0.x; qq[1]=x0.y; qq[2]=x0.z; qq[3]=x0.w;
        qq[4]=x1.x; qq[5]=x1.y; qq[6]=x1.z; qq[7]=x1.w;
        qq[8]=x2.x; qq[9]=x2.y; qq[10]=x2.z; qq[11]=x2.w;
    }
    float Zl = (l4 < npart) ? pZ[(size_t)row * 4 + l4] : 0.f;
    float Z = Zl;
    Z += __shfl_xor(Z, 16, 64);
    Z += __shfl_xor(Z, 32, 64);
    const float es = exp2f(sink_s[h] * LOG2E + KBIAS);
    const float invZ = 1.f / (Z + es);
    const float psink = es * invZ;                // for row l15

    unsigned int idx12[12]; float w12[12];
#pragma unroll
    for (int rd = 0; rd < 12; rd++) {
        unsigned int m = qq[0];
        unsigned int o1 = __shfl_xor(m, 16, 64); m = m > o1 ? m : o1;
        unsigned int o2 = __shfl_xor(m, 32, 64); m = m > o2 ? m : o2;
        const unsigned int hm = m;                // uniform in 4-lane group
        POPQ(qq);
        idx12[rd] = 1023u - (hm & 1023u);
        w12[rd] = (hm == 0u) ? 0.f : exp2f(__uint_as_float(hm & 0xFFFFFC00u)) * invZ;
    }

    // ---- gather marker: lane holds dims [l4*8..+8) and [32+l4*8..+8) of row l15 ----
    const float* kvan = kb + (((size_t)b * 12288 + hk) << 6);
    float mk[16];
#pragma unroll
    for (int i = 0; i < 16; i++) mk[i] = 0.f;
#pragma unroll
    for (int rr = 0; rr < 12; rr++) {
        const float* kr = kvan + (size_t)idx12[rr] * 768 + l4 * 8;
        float4 a0 = *reinterpret_cast<const float4*>(kr);
        float4 a1 = *reinterpret_cast<const float4*>(kr + 4);
        float4 b0 = *reinterpret_cast<const float4*>(kr + 32);
        float4 b1 = *reinterpret_cast<const float4*>(kr + 36);
        float w = w12[rr];
        mk[0] = fmaf(w, a0.x, mk[0]);  mk[1] = fmaf(w, a0.y, mk[1]);
        mk[2] = fmaf(w, a0.z, mk[2]);  mk[3] = fmaf(w, a0.w, mk[3]);
        mk[4] = fmaf(w, a1.x, mk[4]);  mk[5] = fmaf(w, a1.y, mk[5]);
        mk[6] = fmaf(w, a1.z, mk[6]);  mk[7] = fmaf(w, a1.w, mk[7]);
        mk[8] = fmaf(w, b0.x, mk[8]);  mk[9] = fmaf(w, b0.y, mk[9]);
        mk[10] = fmaf(w, b0.z, mk[10]); mk[11] = fmaf(w, b0.w, mk[11]);
        mk[12] = fmaf(w, b1.x, mk[12]); mk[13] = fmaf(w, b1.y, mk[13]);
        mk[14] = fmaf(w, b1.z, mk[14]); mk[15] = fmaf(w, b1.w, mk[15]);
    }
    {
        const float* kr = kvan + (size_t)(tbase + l15) * 768 + l4 * 8;
        float4 a0 = *reinterpret_cast<const float4*>(kr);
        float4 a1 = *reinterpret_cast<const float4*>(kr + 4);
        float4 b0 = *reinterpret_cast<const float4*>(kr + 32);
        float4 b1 = *reinterpret_cast<const float4*>(kr + 36);
        mk[0] += a0.x; mk[1] += a0.y; mk[2] += a0.z; mk[3] += a0.w;
        mk[4] += a1.x; mk[5] += a1.y; mk[6] += a1.z; mk[7] += a1.w;
        mk[8] += b0.x; mk[9] += b0.y; mk[10] += b0.z; mk[11] += b0.w;
        mk[12] += b1.x; mk[13] += b1.y; mk[14] += b1.z; mk[15] += b1.w;
    }
    bf16x8 amk[2];
#pragma unroll
    for (int ks = 0; ks < 2; ks++)
#pragma unroll
        for (int e = 0; e < 8; e++)
            amk[ks][e] = (short)rne_bf16(mk[ks * 8 + e] * (1.f / 13.f));

    // ---- fc: 16 rows x 256 cols, K=64 ----
    f32x4 hacc[16] = {};
#pragma unroll
    for (int ks = 0; ks < 2; ks++)
#pragma unroll
        for (int j = 0; j < 16; j++) {
            bf16x8 bw = *reinterpret_cast<const bf16x8*>(fcw + (j * 16 + l15) * 64 + ks * 32 + l4 * 8);
            hacc[j] = __builtin_amdgcn_mfma_f32_16x16x32_bf16(amk[ks], bw, hacc[j], 0, 0, 0);
        }

    // bias + activation + rmsnorm(256) + gate  (row = l4*4+r, col = j*16+l15)
    float ss[4] = {0.f, 0.f, 0.f, 0.f};
#pragma unroll
    for (int j = 0; j < 16; j++) {
        float bv = fcb[j * 16 + l15];
#pragma unroll
        for (int r = 0; r < 4; r++) {
            float x = hacc[j][r] + bv;
            float y = x * x + 0.75f * x * x * x;
            hacc[j][r] = y;
            ss[r] = fmaf(y, y, ss[r]);
        }
    }
#pragma unroll
    for (int m = 1; m < 16; m <<= 1)
#pragma unroll
        for (int r = 0; r < 4; r++) ss[r] += __shfl_xor(ss[r], m, 64);
    float rinv[4];
#pragma unroll
    for (int r = 0; r < 4; r++)
        rinv[r] = 1.f / sqrtf(ss[r] * (1.f / 256.f) + 1.1920928955078125e-07f);
#pragma unroll
    for (int j = 0; j < 16; j++)
#pragma unroll
        for (int r = 0; r < 4; r++) {
            float z = hacc[j][r] * rinv[r];
            float g = z / (1.f + exp2f(-2.616571036720458f * z));   // MLP_SCALE*log2e
            hsd[wv][l4 * 4 + r][j * 16 + l15] = rne_bf16(g);
        }
    __syncthreads();

    // ---- proj: 16 rows x 64 cols, K=256 ----
    f32x4 oacc[4] = {};
#pragma unroll
    for (int ks = 0; ks < 8; ks++) {
        bf16x8 ah = *reinterpret_cast<const bf16x8*>(&hsd[wv][l15][ks * 32 + l4 * 8]);
#pragma unroll
        for (int j = 0; j < 4; j++) {
            bf16x8 bw = *reinterpret_cast<const bf16x8*>(pw + (j * 16 + l15) * 256 + ks * 32 + l4 * 8);
            oacc[j] = __builtin_amdgcn_mfma_f32_16x16x32_bf16(ah, bw, oacc[j], 0, 0, 0);
        }
    }
#pragma unroll
    for (int j = 0; j < 4; j++) {
        int d = j * 16 + l15;
        float pbv = pb[d];
        float vnv = vn[h * 64 + d];
#pragma unroll
        for (int r = 0; r < 4; r++) {
            int rloc = l4 * 4 + r;
            int t = tbase + rloc;
            float p = __shfl(psink, rloc, 64);    // psink of output row rloc
            float o = oacc[j][r] + pbv + p * vnv;
            ctx[((((size_t)(b << 10) + t) * 48 + h) << 6) + d] = rne_bf16(o);
        }
    }
}

// ---------------------------------------------------------------- launch
extern "C" void kernel_launch(void* const* d_in, const int* in_sizes, int n_in,
                              void* d_out, int out_size, void* d_ws, size_t ws_size,
                              hipStream_t stream) {
    (void)in_sizes; (void)n_in; (void)out_size; (void)ws_size;
    const float* A       = (const float*)d_in[0];
    const float* X       = (const float*)d_in[1];
    const float* Wq_w    = (const float*)d_in[2];
    const float* Wq_b    = (const float*)d_in[3];
    const float* Wk_w    = (const float*)d_in[4];
    const float* Wk_b    = (const float*)d_in[5];
    const float* wedge_A = (const float*)d_in[6];
    const float* wedge_b = (const float*)d_in[7];
    const float* sink    = (const float*)d_in[8];
    const float* v_nulls = (const float*)d_in[9];
    const float* fc_w    = (const float*)d_in[10];
    const float* fc_b    = (const float*)d_in[11];
    const float* proj_w  = (const float*)d_in[12];
    const float* proj_b  = (const float*)d_in[13];
    const float* WO      = (const float*)d_in[14];
    const float* WO_b    = (const float*)d_in[15];
    float* out = (float*)d_out;
    float* ws  = (float*)d_ws;

    // ---- workspace layout (float offsets) ----
    float*          qbuf   = ws;                                  // [0, 6291456) f32; later ctx_bf
    unsigned short* ctx_bf = (unsigned short*)ws;                 //   2048x3072 bf16
    float*          kbbuf  = ws + 6291456;                        // [6291456, 7864320) f32
    unsigned short* q_hi   = (unsigned short*)(ws + 7864320);     // [7864320, 11010048)
    unsigned short* q_lo   = (unsigned short*)(ws + 11010048);    // [11010048, 14155776)
    unsigned short* kf_hi  = (unsigned short*)(ws + 14155776);    // [14155776, 17301504)
    unsigned short* kf_lo  = (unsigned short*)(ws + 17301504);    // [17301504, 20447232)
    // region [20447232, 25559040): early = cvt scratch; late = pZ + pP
    unsigned short* A_bf   = (unsigned short*)(ws + 20447232);
    unsigned short* X_bf   = (unsigned short*)(ws + 21233664);
    unsigned short* Wq_bf  = (unsigned short*)(ws + 22020096);
    unsigned short* Wk_bf  = (unsigned short*)(ws + 23199744);
    float*          Sbuf   = ws + 23494656;
    float*          rcbuf  = ws + 23691264;
    float*          rsbuf  = ws + 23724032;
    float*          pZ     = ws + 20447232;                       // 393216 f32
    unsigned int*   pP     = (unsigned int*)(ws + 20840448);      // 4718592 u32, ends 25559040
    // tail
    float*          wob    = ws + 25559040;
    unsigned short* fcw_bf = (unsigned short*)(ws + 25560064);
    unsigned short* pw_bf  = (unsigned short*)(ws + 25568256);
    unsigned short* WOt_bf = (unsigned short*)(ws + 25576448);
    // end: 26,756,096 floats = 107.0 MB

    prep_all<<<9187, 256, 0, stream>>>(wedge_A, wedge_b, WO_b,
                                       A, X, Wq_w, Wk_w, fc_w, proj_w, WO,
                                       Sbuf, rcbuf, rsbuf, wob,
                                       A_bf, X_bf, Wq_bf, Wk_bf, fcw_bf, pw_bf, WOt_bf);
    gemm_qk<<<dim3(30, 16), 256, 0, stream>>>(A_bf, Wq_bf, Wq_b, qbuf,
                                              X_bf, Wk_bf, Wk_b, kbbuf);
    transform_qk<<<3072, 256, 0, stream>>>(qbuf, kbbuf, Sbuf, rcbuf, rsbuf,
                                           q_hi, q_lo, kf_hi, kf_lo);
    attn_scores<<<7680, 64, 0, stream>>>(q_hi, q_lo, kf_hi, kf_lo, pZ, pP);
    mlp_fused<<<3072, 128, 0, stream>>>(pP, pZ, sink, kbbuf,
                                        fcw_bf, fc_b, pw_bf, proj_b, v_nulls, ctx_bf);
    gemm_bf16_64<<<dim3(12, 32), 256, 0, stream>>>(ctx_bf, WOt_bf, wob, out, 2048, 768, 3072, 0.25f);
}

// Round 13
// 291.154 us; speedup vs baseline: 1.2050x; 1.2050x over previous
//
#include <hip/hip_runtime.h>
#include <math.h>

#define B_   2
#define T_   1024
#define C_   768
#define DH_  64
#define NH_  12
#define HT_  48

typedef short bf16x8 __attribute__((ext_vector_type(8)));
typedef float f32x4 __attribute__((ext_vector_type(4)));

__device__ __forceinline__ float wave_sum(float v) {
#pragma unroll
    for (int off = 32; off; off >>= 1) v += __shfl_xor(v, off, 64);
    return v;
}
__device__ __forceinline__ unsigned short rne_bf16(float f) {
    unsigned u = __float_as_uint(f);
    return (unsigned short)((u + 0x7FFFu + ((u >> 16) & 1u)) >> 16);
}
__device__ __forceinline__ float bf2f(unsigned short u) {
    return __uint_as_float((unsigned)u << 16);
}

#define LOG2E 1.4426950408889634f
#define KBIAS 32.0f

// work tables: 40 (tile,part) units per (b,h), heavy-first. chunk = 64 cols, part = 4 chunks.
__constant__ int c_tileTab[40] = {15,15,15,15, 14,14,14, 13,13,13, 12,12,12, 11,11,11,
                                  10,10, 9,9, 8,8, 7,7, 6, 5, 4, 3,
                                  14,10,6,2, 13,9,5,1, 12,8,4,0};
__constant__ int c_partTab[40] = { 0, 1, 2, 3,  0, 1, 2,  0, 1, 2,  0, 1, 2,  0, 1, 2,
                                   0, 1, 0,1, 0,1, 0,1, 0, 0, 0, 0,
                                   3, 2,1,0,  3,2,1,0,  3,2,1,0};

// ---------------------------------------------------------------- fused prep: wo_transpose + cvt + S/rope/wob
__global__ __launch_bounds__(256) void prep_all(
    const float* __restrict__ wA, const float* __restrict__ wb, const float* __restrict__ WOb,
    const float* __restrict__ A, const float* __restrict__ X,
    const float* __restrict__ Wq, const float* __restrict__ Wk,
    const float* __restrict__ fcw, const float* __restrict__ pw, const float* __restrict__ WO,
    float* __restrict__ S, float* __restrict__ rc, float* __restrict__ rs, float* __restrict__ wob,
    unsigned short* __restrict__ Ab, unsigned short* __restrict__ Xb,
    unsigned short* __restrict__ Wqb, unsigned short* __restrict__ Wkb,
    unsigned short* __restrict__ fcb, unsigned short* __restrict__ pwb,
    unsigned short* __restrict__ WOt) {
    __shared__ float tl[32][33];
    const int bid = blockIdx.x;
    if (bid < 2304) {               // WO transpose (4,768,768) -> WOt[d][n*768+c] bf16
        const int n = bid / 576, rem = bid % 576;
        const int d0 = (rem / 24) * 32, c0 = (rem % 24) * 32;
        const int tx = threadIdx.x & 31, ty = threadIdx.x >> 5;
#pragma unroll
        for (int p = 0; p < 4; p++)
            tl[ty + p * 8][tx] = WO[(size_t)n * 589824 + (size_t)(c0 + ty + p * 8) * 768 + d0 + tx];
        __syncthreads();
#pragma unroll
        for (int p = 0; p < 4; p++)
            WOt[(size_t)(d0 + ty + p * 8) * 3072 + n * 768 + c0 + tx] = rne_bf16(tl[tx][ty + p * 8]);
    } else if (bid < 8288) {        // f32 -> bf16 conversions, float4 granularity
        int i = (bid - 2304) * 256 + threadIdx.x;
        const float* s; unsigned short* d; int o;
        if (i < 393216)       { s = A;   d = Ab;  o = i; }
        else if (i < 786432)  { s = X;   d = Xb;  o = i - 393216; }
        else if (i < 1376256) { s = Wq;  d = Wqb; o = i - 786432; }
        else if (i < 1523712) { s = Wk;  d = Wkb; o = i - 1376256; }
        else if (i < 1527808) { s = fcw; d = fcb; o = i - 1523712; }
        else if (i < 1531904) { s = pw;  d = pwb; o = i - 1527808; }
        else return;
        float4 v = reinterpret_cast<const float4*>(s)[o];
        ushort4 u;
        u.x = rne_bf16(v.x); u.y = rne_bf16(v.y); u.z = rne_bf16(v.z); u.w = rne_bf16(v.w);
        reinterpret_cast<ushort4*>(d)[o] = u;
    } else {                        // S, rope tables, wob
        int i = (bid - 8288) * 256 + threadIdx.x;
        if (i < HT_ * 64 * 64) {
            int e = i & 63, d = (i >> 6) & 63, h = i >> 12;
            float v = wA[d * 64 + e] - wA[e * 64 + d];
            if (d == e) v += wb[h * 64 + d];
            S[i] = v;
        } else if (i < HT_ * 64 * 64 + T_ * 32) {
            int j = i - HT_ * 64 * 64;
            int t = j >> 5, f = j & 31;
            float invf = (float)(1.0 / pow(10000.0, (double)f / 32.0));
            float fr = (float)t * invf;
            rc[j] = cosf(fr);
            rs[j] = sinf(fr);
        } else if (i < HT_ * 64 * 64 + T_ * 32 + C_) {
            int d = i - (HT_ * 64 * 64 + T_ * 32);
            wob[d] = WOb[d] + WOb[C_ + d] + WOb[2 * C_ + d] + WOb[3 * C_ + d];
        }
    }
}

// ---------------------------------------------------------------- q-proj + k-proj in one grid (128x128 MFMA, K=768)
// k-branch also emits vanilla-k bf16 copy kvb in (b,hk,t,64) layout.
__global__ __launch_bounds__(256) void gemm_qk(
    const unsigned short* __restrict__ Aq, const unsigned short* __restrict__ Wqw,
    const float* __restrict__ bq, float* __restrict__ Cq,
    const unsigned short* __restrict__ Ak, const unsigned short* __restrict__ Wkw,
    const float* __restrict__ bk, float* __restrict__ Ck,
    unsigned short* __restrict__ kvb) {
    __shared__ unsigned short Asd[128][40];
    __shared__ unsigned short Bsd[128][40];
    int bx = blockIdx.x;
    const bool isK = (bx >= 24);
    const unsigned short *A, *W; const float* bias; float* C; int N;
    if (!isK) { A = Aq; W = Wqw; bias = bq; C = Cq; N = 3072; }
    else { bx -= 24; A = Ak; W = Wkw; bias = bk; C = Ck; N = 768; }
    const int K = 768;
    const int tid = threadIdx.x;
    const int wv = tid >> 6, lane = tid & 63;
    const int m0 = blockIdx.y * 128, n0 = bx * 128;
    const int wr = (wv >> 1) * 64, wc = (wv & 1) * 64;
    const int l15 = lane & 15, l4 = lane >> 4;
    const int srow = tid >> 2, soff = (tid & 3) * 8;
    f32x4 acc[4][4] = {};
    for (int k0 = 0; k0 < K; k0 += 32) {
        uint4 a0 = *reinterpret_cast<const uint4*>(A + (size_t)(m0 + srow) * K + k0 + soff);
        uint4 a1 = *reinterpret_cast<const uint4*>(A + (size_t)(m0 + srow + 64) * K + k0 + soff);
        uint4 b0 = *reinterpret_cast<const uint4*>(W + (size_t)(n0 + srow) * K + k0 + soff);
        uint4 b1 = *reinterpret_cast<const uint4*>(W + (size_t)(n0 + srow + 64) * K + k0 + soff);
        *reinterpret_cast<uint4*>(&Asd[srow][soff])      = a0;
        *reinterpret_cast<uint4*>(&Asd[srow + 64][soff]) = a1;
        *reinterpret_cast<uint4*>(&Bsd[srow][soff])      = b0;
        *reinterpret_cast<uint4*>(&Bsd[srow + 64][soff]) = b1;
        __syncthreads();
        bf16x8 af[4], bfr[4];
#pragma unroll
        for (int i = 0; i < 4; i++)
            af[i] = *reinterpret_cast<const bf16x8*>(&Asd[wr + i * 16 + l15][l4 * 8]);
#pragma unroll
        for (int j = 0; j < 4; j++)
            bfr[j] = *reinterpret_cast<const bf16x8*>(&Bsd[wc + j * 16 + l15][l4 * 8]);
#pragma unroll
        for (int i = 0; i < 4; i++)
#pragma unroll
            for (int j = 0; j < 4; j++)
                acc[i][j] = __builtin_amdgcn_mfma_f32_16x16x32_bf16(af[i], bfr[j], acc[i][j], 0, 0, 0);
        __syncthreads();
    }
#pragma unroll
    for (int i = 0; i < 4; i++)
#pragma unroll
        for (int j = 0; j < 4; j++) {
            int col = n0 + wc + j * 16 + l15;
            float bv = bias[col];
#pragma unroll
            for (int r = 0; r < 4; r++) {
                int row = m0 + wr + i * 16 + l4 * 4 + r;
                float o = acc[i][j][r] + bv;
                C[(size_t)row * N + col] = o;
                if (isK) {
                    int hk2 = col >> 6, d2 = col & 63;
                    int bb = row >> 10, tt = row & 1023;
                    kvb[((((size_t)(bb * 12 + hk2)) << 10) + tt) * 64 + d2] = rne_bf16(o);
                }
            }
        }
}

// ---------------------------------------------------------------- WO GEMM split-K=4: partials (no bias/scale)
__global__ __launch_bounds__(256) void gemm_wo_splitk(const unsigned short* __restrict__ A,
                                                      const unsigned short* __restrict__ W,
                                                      float* __restrict__ Cp) {
    __shared__ unsigned short Asd[64][40];
    __shared__ unsigned short Bsd[64][40];
    const int tid = threadIdx.x;
    const int wv = tid >> 6, lane = tid & 63;
    const int m0 = blockIdx.y * 64, n0 = blockIdx.x * 64, z = blockIdx.z;
    const int l15 = lane & 15, l4 = lane >> 4;
    const int srow = tid >> 2, soff = (tid & 3) * 8;
    const int K = 3072;
    float* C = Cp + (size_t)z * 1572864;
    f32x4 acc[4] = {};
    for (int k0 = z * 768; k0 < z * 768 + 768; k0 += 32) {
        uint4 a0 = *reinterpret_cast<const uint4*>(A + (size_t)(m0 + srow) * K + k0 + soff);
        uint4 b0 = *reinterpret_cast<const uint4*>(W + (size_t)(n0 + srow) * K + k0 + soff);
        *reinterpret_cast<uint4*>(&Asd[srow][soff]) = a0;
        *reinterpret_cast<uint4*>(&Bsd[srow][soff]) = b0;
        __syncthreads();
        bf16x8 af = *reinterpret_cast<const bf16x8*>(&Asd[wv * 16 + l15][l4 * 8]);
#pragma unroll
        for (int j = 0; j < 4; j++) {
            bf16x8 bfr = *reinterpret_cast<const bf16x8*>(&Bsd[j * 16 + l15][l4 * 8]);
            acc[j] = __builtin_amdgcn_mfma_f32_16x16x32_bf16(af, bfr, acc[j], 0, 0, 0);
        }
        __syncthreads();
    }
#pragma unroll
    for (int j = 0; j < 4; j++) {
        int col = n0 + j * 16 + l15;
#pragma unroll
        for (int r = 0; r < 4; r++) {
            int row = m0 + wv * 16 + l4 * 4 + r;
            C[(size_t)row * 768 + col] = acc[j][r];
        }
    }
}

// ---------------------------------------------------------------- WO reduce: out = (p0+p1+p2+p3 + wob) * 0.25
__global__ __launch_bounds__(256) void wo_reduce(const float* __restrict__ Cp,
                                                 const float* __restrict__ wob,
                                                 float* __restrict__ out) {
    int i = blockIdx.x * 256 + threadIdx.x;   // float4 index, 393216 total
    const float4* p0 = reinterpret_cast<const float4*>(Cp);
    const float4* p1 = reinterpret_cast<const float4*>(Cp + 1572864);
    const float4* p2 = reinterpret_cast<const float4*>(Cp + 3145728);
    const float4* p3 = reinterpret_cast<const float4*>(Cp + 4718592);
    float4 a = p0[i], b = p1[i], c = p2[i], d = p3[i];
    float4 w = reinterpret_cast<const float4*>(wob)[i % 192];
    float4 o;
    o.x = (a.x + b.x + c.x + d.x + w.x) * 0.25f;
    o.y = (a.y + b.y + c.y + d.y + w.y) * 0.25f;
    o.z = (a.z + b.z + c.z + d.z + w.z) * 0.25f;
    o.w = (a.w + b.w + c.w + d.w + w.w) * 0.25f;
    reinterpret_cast<float4*>(out)[i] = o;
}

// ---------------------------------------------------------------- q + k transforms in one grid
__global__ __launch_bounds__(256) void transform_qk(
    const float* __restrict__ qb, const float* __restrict__ kbv, const float* __restrict__ S,
    const float* __restrict__ rc, const float* __restrict__ rs,
    unsigned short* __restrict__ qhi, unsigned short* __restrict__ qlo,
    unsigned short* __restrict__ khi, unsigned short* __restrict__ klo) {
    const int tid = threadIdx.x, wv = tid >> 6, lane = tid & 63;
    const bool isQ = blockIdx.x < 1536;
    const int bidx = isQ ? blockIdx.x : blockIdx.x - 1536;
    const int h = bidx >> 5, blk = bidx & 31;
    const int hk = h % 12;
    __shared__ float Sl[4096];
    __shared__ float sh[4][64];
    const float4* Sg = reinterpret_cast<const float4*>(S + h * 4096);
#pragma unroll
    for (int i = 0; i < 4; i++)
        reinterpret_cast<float4*>(Sl)[tid + 256 * i] = Sg[tid + 256 * i];
    __syncthreads();
    unsigned short* ohi = isQ ? qhi : khi;
    unsigned short* olo = isQ ? qlo : klo;
    for (int it = 0; it < 16; ++it) {
        int r = (blk << 6) + (wv << 4) + it;   // 0..2047
        int b = r >> 10, t = r & 1023;
        float v;
        if (isQ) {
            v = qb[((((size_t)(b << 10) + t) * 48 + h) << 6) + lane];
            float ss = wave_sum(v * v);
            v *= 1.f / sqrtf(ss * (1.f / 64.f) + 1.1920928955078125e-07f);
        } else {
            v = kbv[((((size_t)(b << 10) + t) * 12 + hk) << 6) + lane];
        }
        sh[wv][lane] = v;
        float acc = v;
#pragma unroll 8
        for (int d = 0; d < 64; d++) acc = fmaf(sh[wv][d], Sl[(d << 6) + lane], acc);
        sh[wv][lane] = acc;
        int j = lane & 31;
        float x1 = sh[wv][2 * j], x2 = sh[wv][2 * j + 1];
        float ct = rc[t * 32 + j], st = rs[t * 32 + j];
        float o = (lane < 32) ? (x1 * ct - x2 * st) : (x1 * st + x2 * ct);
        if (isQ) o *= 0.125f * LOG2E;          // exp2 domain
        unsigned short oh = rne_bf16(o);
        unsigned short ol = rne_bf16(o - bf2f(oh));
        size_t oidx = ((((size_t)(b * 48 + h)) << 10) + t) * 64 + lane;
        ohi[oidx] = oh;
        olo[oidx] = ol;
    }
}

#define POPQ(qq)                                                                  \
    {                                                                             \
        bool tk = (qq[0] == hm);                                                  \
        qq[0]=tk?qq[1]:qq[0]; qq[1]=tk?qq[2]:qq[1]; qq[2]=tk?qq[3]:qq[2];         \
        qq[3]=tk?qq[4]:qq[3]; qq[4]=tk?qq[5]:qq[4]; qq[5]=tk?qq[6]:qq[5];         \
        qq[6]=tk?qq[7]:qq[6]; qq[7]=tk?qq[8]:qq[7]; qq[8]=tk?qq[9]:qq[8];         \
        qq[9]=tk?qq[10]:qq[9]; qq[10]=tk?qq[11]:qq[10]; qq[11]=tk?0u:qq[11];      \
    }

#define TOP12INS(pln, pk)                                                         \
    {                                                                             \
        unsigned _p = (pk);                                                       \
        _Pragma("unroll")                                                         \
        for (int jj = 0; jj < 12; jj++) {                                         \
            unsigned mx = pln[jj] > _p ? pln[jj] : _p;                            \
            _p = pln[jj] > _p ? _p : pln[jj];                                     \
            pln[jj] = mx;                                                         \
        }                                                                         \
    }

// ---------------------------------------------------------------- phase A: MFMA scores, exp2 domain, +KBIAS in acc
// r6-measured launch shape: ONE wave per 64-thread block, natural unit map
// (moderate occupancy keeps the concurrent k working set within L2; higher
// occupancy measured to thrash L2: FETCH 52->238->375MB r6/r8/r9).
__global__ __launch_bounds__(64, 3) void attn_scores(
    const unsigned short* __restrict__ qhi, const unsigned short* __restrict__ qlo,
    const unsigned short* __restrict__ khi, const unsigned short* __restrict__ klo,
    float* __restrict__ pZ, unsigned int* __restrict__ pP) {
    const int lane = threadIdx.x;
    const int bid = blockIdx.x;
    const int u = bid / 96, bh = bid % 96;
    const int tile = c_tileTab[u >> 1], part = c_partTab[u >> 1], half = u & 1;
    const int l15 = lane & 15, l4 = lane >> 4;
    const int t0 = (tile << 6) + (half << 5);
    const int c0 = part << 2;
    const int c1 = min(c0 + 4, tile + 1);
    const size_t base = ((size_t)bh) << 16;

    bf16x8 qh8[2][2], ql8[2][2];
#pragma unroll
    for (int ni = 0; ni < 2; ni++)
#pragma unroll
        for (int ks = 0; ks < 2; ks++) {
            size_t off = base + (size_t)(t0 + ni * 16 + l15) * 64 + ks * 32 + l4 * 8;
            qh8[ni][ks] = *reinterpret_cast<const bf16x8*>(qhi + off);
            ql8[ni][ks] = *reinterpret_cast<const bf16x8*>(qlo + off);
        }

    unsigned int pl[2][12];
#pragma unroll
    for (int ni = 0; ni < 2; ni++)
#pragma unroll
        for (int i = 0; i < 12; i++) pl[ni][i] = 0u;
    float Zp[2] = {0.f, 0.f};

    for (int cc = c0; cc < c1; ++cc) {
        f32x4 acc[4][2];
#pragma unroll
        for (int mi = 0; mi < 4; mi++)
#pragma unroll
            for (int ni = 0; ni < 2; ni++)
                acc[mi][ni] = (f32x4){KBIAS, KBIAS, KBIAS, KBIAS};
#pragma unroll
        for (int ks = 0; ks < 2; ks++) {
            bf16x8 kh8[4], kl8[4];
#pragma unroll
            for (int mi = 0; mi < 4; mi++) {
                size_t off = base + (size_t)((cc << 6) + mi * 16 + l15) * 64 + ks * 32 + l4 * 8;
                kh8[mi] = *reinterpret_cast<const bf16x8*>(khi + off);
                kl8[mi] = *reinterpret_cast<const bf16x8*>(klo + off);
            }
#pragma unroll
            for (int mi = 0; mi < 4; mi++)
#pragma unroll
                for (int ni = 0; ni < 2; ni++) {
                    acc[mi][ni] = __builtin_amdgcn_mfma_f32_16x16x32_bf16(kh8[mi], qh8[ni][ks], acc[mi][ni], 0, 0, 0);
                    acc[mi][ni] = __builtin_amdgcn_mfma_f32_16x16x32_bf16(kh8[mi], ql8[ni][ks], acc[mi][ni], 0, 0, 0);
                    acc[mi][ni] = __builtin_amdgcn_mfma_f32_16x16x32_bf16(kl8[mi], qh8[ni][ks], acc[mi][ni], 0, 0, 0);
                }
        }
        if (cc == tile) {   // diagonal chunk: causal mask
#pragma unroll
            for (int ni = 0; ni < 2; ni++) {
                const int tq = t0 + ni * 16 + l15;
#pragma unroll
                for (int mi = 0; mi < 4; mi++)
#pragma unroll
                    for (int r = 0; r < 4; r++) {
                        int kcol = (cc << 6) + mi * 16 + l4 * 4 + r;
                        float s = acc[mi][ni][r];
                        bool ok = kcol <= tq;
                        float e = exp2f(s);
                        Zp[ni] += ok ? e : 0.f;
                        unsigned pk = (__float_as_uint(s) & 0xFFFFFC00u) | (unsigned)(1023 - kcol);
                        pk = ok ? pk : 0u;
                        TOP12INS(pl[ni], pk);
                    }
            }
        } else {            // interior chunk: all valid
#pragma unroll
            for (int ni = 0; ni < 2; ni++) {
#pragma unroll
                for (int mi = 0; mi < 4; mi++)
#pragma unroll
                    for (int r = 0; r < 4; r++) {
                        int kcol = (cc << 6) + mi * 16 + l4 * 4 + r;
                        float s = acc[mi][ni][r];
                        Zp[ni] += exp2f(s);
                        unsigned pk = (__float_as_uint(s) & 0xFFFFFC00u) | (unsigned)(1023 - kcol);
                        TOP12INS(pl[ni], pk);
                    }
            }
        }
    }

    // in-wave 4-lane merge per qrow (single wave per block)
    __shared__ unsigned int lsh[64][2][12];
    __shared__ float zsh[64][2];
#pragma unroll
    for (int ni = 0; ni < 2; ni++) {
#pragma unroll
        for (int i = 0; i < 12; i++) lsh[lane][ni][i] = pl[ni][i];
        zsh[lane][ni] = Zp[ni];
    }
    __syncthreads();
    if (lane < 32) {
        const int ni = lane >> 4, c = lane & 15;
        unsigned int m0[12], m1[12], m2[12], m3[12];
#pragma unroll
        for (int i = 0; i < 12; i++) {
            m0[i] = lsh[c][ni][i];
            m1[i] = lsh[c + 16][ni][i];
            m2[i] = lsh[c + 32][ni][i];
            m3[i] = lsh[c + 48][ni][i];
        }
        float Z = zsh[c][ni] + zsh[c + 16][ni] + zsh[c + 32][ni] + zsh[c + 48][ni];
        unsigned int out[12];
#pragma unroll
        for (int rd = 0; rd < 12; rd++) {
            unsigned int ha = m0[0] > m1[0] ? m0[0] : m1[0];
            unsigned int hb2 = m2[0] > m3[0] ? m2[0] : m3[0];
            unsigned int hm = ha > hb2 ? ha : hb2;
            POPQ(m0); POPQ(m1); POPQ(m2); POPQ(m3);
            out[rd] = hm;
        }
        const size_t r = (((size_t)bh) << 10) + t0 + lane;
        pZ[r * 4 + part] = Z;
        unsigned int* pp = pP + r * 48 + part * 12;
        *reinterpret_cast<uint4*>(pp + 0) = make_uint4(out[0], out[1], out[2], out[3]);
        *reinterpret_cast<uint4*>(pp + 4) = make_uint4(out[4], out[5], out[6], out[7]);
        *reinterpret_cast<uint4*>(pp + 8) = make_uint4(out[8], out[9], out[10], out[11]);
    }
}

// ---------------------------------------------------------------- fused merge + COALESCED gather + fc + act + proj
// 256 threads / 4 waves (r10-measured shape). Per wave: 16 rows.
// Merge: lane l15 = row, l4 = part queue; (idx,w) published to LDS.
// Gather: lane (g=l4, i=l15): group g reads ONE bf16 k-row per instr, lane i
// holds dims [4i,4i+4) -> 1 cache line per row, 4 lines/instr (vs 16 before).
// Transpose to MFMA A-frag layout via per-wave LDS scratch (overlaid w/ hsd).
__global__ __launch_bounds__(256, 2) void mlp_fused(
    const unsigned int* __restrict__ pP, const float* __restrict__ pZ,
    const float* __restrict__ sink_s, const unsigned short* __restrict__ kvb,
    const unsigned short* __restrict__ fcw, const float* __restrict__ fcb,
    const unsigned short* __restrict__ pw, const float* __restrict__ pb,
    const float* __restrict__ vn, unsigned short* __restrict__ ctx) {
    const int tid = threadIdx.x, wv = tid >> 6, lane = tid & 63;
    const int l15 = lane & 15, l4 = lane >> 4;
    const int wid = blockIdx.x * 4 + wv;          // 0..6143
    const int r0 = wid << 4;
    const int bh = wid >> 6;
    const int h = bh % 48, b = bh / 48, hk = h % 12;
    const int tbase = r0 & 1023;
    const int tile = tbase >> 6;
    const int npart = (tile >> 2) + 1;            // wave-uniform
    __shared__ __align__(16) char scratch[4][8704];  // phase D: f32[16][68]; phase E: u16[16][272]
    __shared__ unsigned int idwi[4][16][12];
    __shared__ float idww[4][16][12];

    // ---- phase A: part-merge; publish (idx,w) to LDS ----
    const int row = r0 + l15;
    unsigned int qq[12];
    {
        const bool val = l4 < npart;
        uint4 x0 = make_uint4(0,0,0,0), x1 = x0, x2 = x0;
        if (val) {
            const uint4* ip = reinterpret_cast<const uint4*>(pP + (size_t)row * 48 + l4 * 12);
            x0 = ip[0]; x1 = ip[1]; x2 = ip[2];
        }
        qq[0]=x0.x; qq[1]=x0.y; qq[2]=x0.z; qq[3]=x0.w;
        qq[4]=x1.x; qq[5]=x1.y; qq[6]=x1.z; qq[7]=x1.w;
        qq[8]=x2.x; qq[9]=x2.y; qq[10]=x2.z; qq[11]=x2.w;
    }
    float Zl = (l4 < npart) ? pZ[(size_t)row * 4 + l4] : 0.f;
    float Z = Zl;
    Z += __shfl_xor(Z, 16, 64);
    Z += __shfl_xor(Z, 32, 64);
    const float es = exp2f(sink_s[h] * LOG2E + KBIAS);
    const float invZ = 1.f / (Z + es);
    const float psink = es * invZ;                // for row l15

#pragma unroll
    for (int rd = 0; rd < 12; rd++) {
        unsigned int m = qq[0];
        unsigned int o1 = __shfl_xor(m, 16, 64); m = m > o1 ? m : o1;
        unsigned int o2 = __shfl_xor(m, 32, 64); m = m > o2 ? m : o2;
        const unsigned int hm = m;                // uniform in 4-lane group
        POPQ(qq);
        if (l4 == 0) {
            idwi[wv][l15][rd] = 1023u - (hm & 1023u);
            idww[wv][l15][rd] = (hm == 0u) ? 0.f : exp2f(__uint_as_float(hm & 0xFFFFFC00u)) * invZ;
        }
    }
    __syncthreads();

    // ---- phase C: coalesced gather from bf16 kvb ----
    const unsigned short* kvroot = kvb + (((size_t)(b * 12 + hk)) << 16);
    float acc4[4][4];
#pragma unroll
    for (int i = 0; i < 4; i++)
#pragma unroll
        for (int e = 0; e < 4; e++) acc4[i][e] = 0.f;
#pragma unroll
    for (int rsub = 0; rsub < 4; rsub++) {
        const int grow = rsub * 4 + l4;           // row 0..15 handled by this group
#pragma unroll
        for (int rr = 0; rr < 12; rr++) {
            unsigned idx = idwi[wv][grow][rr];
            float w = idww[wv][grow][rr];
            ushort4 kv = *reinterpret_cast<const ushort4*>(kvroot + ((size_t)idx << 6) + l15 * 4);
            acc4[rsub][0] = fmaf(w, bf2f(kv.x), acc4[rsub][0]);
            acc4[rsub][1] = fmaf(w, bf2f(kv.y), acc4[rsub][1]);
            acc4[rsub][2] = fmaf(w, bf2f(kv.z), acc4[rsub][2]);
            acc4[rsub][3] = fmaf(w, bf2f(kv.w), acc4[rsub][3]);
        }
        ushort4 kv = *reinterpret_cast<const ushort4*>(kvroot + ((size_t)(tbase + grow) << 6) + l15 * 4);
        acc4[rsub][0] = (acc4[rsub][0] + bf2f(kv.x)) * (1.f / 13.f);
        acc4[rsub][1] = (acc4[rsub][1] + bf2f(kv.y)) * (1.f / 13.f);
        acc4[rsub][2] = (acc4[rsub][2] + bf2f(kv.z)) * (1.f / 13.f);
        acc4[rsub][3] = (acc4[rsub][3] + bf2f(kv.w)) * (1.f / 13.f);
    }

    // ---- phase D: transpose to MFMA layout via per-wave LDS ----
    float* mkls = reinterpret_cast<float*>(scratch[wv]);   // [16][68]
#pragma unroll
    for (int rsub = 0; rsub < 4; rsub++)
        *reinterpret_cast<float4*>(&mkls[(rsub * 4 + l4) * 68 + l15 * 4]) =
            make_float4(acc4[rsub][0], acc4[rsub][1], acc4[rsub][2], acc4[rsub][3]);
    __syncthreads();
    bf16x8 amk[2];
#pragma unroll
    for (int ks = 0; ks < 2; ks++) {
        float4 f0 = *reinterpret_cast<const float4*>(&mkls[l15 * 68 + ks * 32 + l4 * 8]);
        float4 f1 = *reinterpret_cast<const float4*>(&mkls[l15 * 68 + ks * 32 + l4 * 8 + 4]);
        amk[ks][0] = (short)rne_bf16(f0.x); amk[ks][1] = (short)rne_bf16(f0.y);
        amk[ks][2] = (short)rne_bf16(f0.z); amk[ks][3] = (short)rne_bf16(f0.w);
        amk[ks][4] = (short)rne_bf16(f1.x); amk[ks][5] = (short)rne_bf16(f1.y);
        amk[ks][6] = (short)rne_bf16(f1.z); amk[ks][7] = (short)rne_bf16(f1.w);
    }
    __syncthreads();

    // ---- fc: 16 rows x 256 cols, K=64 ----
    f32x4 hacc[16] = {};
#pragma unroll
    for (int ks = 0; ks < 2; ks++)
#pragma unroll
        for (int j = 0; j < 16; j++) {
            bf16x8 bw = *reinterpret_cast<const bf16x8*>(fcw + (j * 16 + l15) * 64 + ks * 32 + l4 * 8);
            hacc[j] = __builtin_amdgcn_mfma_f32_16x16x32_bf16(amk[ks], bw, hacc[j], 0, 0, 0);
        }

    // bias + activation + rmsnorm(256) + gate  (row = l4*4+r, col = j*16+l15)
    float ss[4] = {0.f, 0.f, 0.f, 0.f};
#pragma unroll
    for (int j = 0; j < 16; j++) {
        float bv = fcb[j * 16 + l15];
#pragma unroll
        for (int r = 0; r < 4; r++) {
            float x = hacc[j][r] + bv;
            float y = x * x + 0.75f * x * x * x;
            hacc[j][r] = y;
            ss[r] = fmaf(y, y, ss[r]);
        }
    }
#pragma unroll
    for (int m = 1; m < 16; m <<= 1)
#pragma unroll
        for (int r = 0; r < 4; r++) ss[r] += __shfl_xor(ss[r], m, 64);
    float rinv[4];
#pragma unroll
    for (int r = 0; r < 4; r++)
        rinv[r] = 1.f / sqrtf(ss[r] * (1.f / 256.f) + 1.1920928955078125e-07f);
    unsigned short (*hsd)[272] = reinterpret_cast<unsigned short (*)[272]>(scratch[wv]);
#pragma unroll
    for (int j = 0; j < 16; j++)
#pragma unroll
        for (int r = 0; r < 4; r++) {
            float z = hacc[j][r] * rinv[r];
            float g = z / (1.f + exp2f(-2.616571036720458f * z));   // MLP_SCALE*log2e
            hsd[l4 * 4 + r][j * 16 + l15] = rne_bf16(g);
        }
    __syncthreads();

    // ---- proj: 16 rows x 64 cols, K=256 ----
    f32x4 oacc[4] = {};
#pragma unroll
    for (int ks = 0; ks < 8; ks++) {
        bf16x8 ah = *reinterpret_cast<const bf16x8*>(&hsd[l15][ks * 32 + l4 * 8]);
#pragma unroll
        for (int j = 0; j < 4; j++) {
            bf16x8 bw = *reinterpret_cast<const bf16x8*>(pw + (j * 16 + l15) * 256 + ks * 32 + l4 * 8);
            oacc[j] = __builtin_amdgcn_mfma_f32_16x16x32_bf16(ah, bw, oacc[j], 0, 0, 0);
        }
    }
#pragma unroll
    for (int j = 0; j < 4; j++) {
        int d = j * 16 + l15;
        float pbv = pb[d];
        float vnv = vn[h * 64 + d];
#pragma unroll
        for (int r = 0; r < 4; r++) {
            int rloc = l4 * 4 + r;
            int t = tbase + rloc;
            float p = __shfl(psink, rloc, 64);    // psink of output row rloc
            float o = oacc[j][r] + pbv + p * vnv;
            ctx[((((size_t)(b << 10) + t) * 48 + h) << 6) + d] = rne_bf16(o);
        }
    }
}

// ---------------------------------------------------------------- launch
extern "C" void kernel_launch(void* const* d_in, const int* in_sizes, int n_in,
                              void* d_out, int out_size, void* d_ws, size_t ws_size,
                              hipStream_t stream) {
    (void)in_sizes; (void)n_in; (void)out_size; (void)ws_size;
    const float* A       = (const float*)d_in[0];
    const float* X       = (const float*)d_in[1];
    const float* Wq_w    = (const float*)d_in[2];
    const float* Wq_b    = (const float*)d_in[3];
    const float* Wk_w    = (const float*)d_in[4];
    const float* Wk_b    = (const float*)d_in[5];
    const float* wedge_A = (const float*)d_in[6];
    const float* wedge_b = (const float*)d_in[7];
    const float* sink    = (const float*)d_in[8];
    const float* v_nulls = (const float*)d_in[9];
    const float* fc_w    = (const float*)d_in[10];
    const float* fc_b    = (const float*)d_in[11];
    const float* proj_w  = (const float*)d_in[12];
    const float* proj_b  = (const float*)d_in[13];
    const float* WO      = (const float*)d_in[14];
    const float* WO_b    = (const float*)d_in[15];
    float* out = (float*)d_out;
    float* ws  = (float*)d_ws;

    // ---- workspace layout (float offsets) ----
    float*          qbuf   = ws;                                  // [0, 6291456) f32; later ctx_bf
    unsigned short* ctx_bf = (unsigned short*)ws;                 //   2048x3072 bf16
    float*          kbbuf  = ws + 6291456;                        // [6291456, 7864320) f32
    unsigned short* q_hi   = (unsigned short*)(ws + 7864320);     // [7864320, 11010048)
    float*          wop    = ws + 7864320;                        //   WO split-K partials (4x1572864), overlays q/k bf16
    unsigned short* q_lo   = (unsigned short*)(ws + 11010048);    // [11010048, 14155776)
    unsigned short* kf_hi  = (unsigned short*)(ws + 14155776);    // [14155776, 17301504)
    unsigned short* kf_lo  = (unsigned short*)(ws + 17301504);    // [17301504, 20447232)
    // region [20447232, 25559040): early = cvt scratch; late = pZ + pP
    unsigned short* A_bf   = (unsigned short*)(ws + 20447232);
    unsigned short* X_bf   = (unsigned short*)(ws + 21233664);
    unsigned short* Wq_bf  = (unsigned short*)(ws + 22020096);
    unsigned short* Wk_bf  = (unsigned short*)(ws + 23199744);
    float*          Sbuf   = ws + 23494656;
    float*          rcbuf  = ws + 23691264;
    float*          rsbuf  = ws + 23724032;
    float*          pZ     = ws + 20447232;                       // 393216 f32
    unsigned int*   pP     = (unsigned int*)(ws + 20840448);      // 4718592 u32, ends 25559040
    // tail
    float*          wob    = ws + 25559040;
    unsigned short* fcw_bf = (unsigned short*)(ws + 25560064);
    unsigned short* pw_bf  = (unsigned short*)(ws + 25568256);
    unsigned short* WOt_bf = (unsigned short*)(ws + 25576448);    // ends 26756096
    unsigned short* kvb    = (unsigned short*)(ws + 26756096);    // 1572864 u16 -> ends 27542528 (107MB+3MB)

    prep_all<<<9187, 256, 0, stream>>>(wedge_A, wedge_b, WO_b,
                                       A, X, Wq_w, Wk_w, fc_w, proj_w, WO,
                                       Sbuf, rcbuf, rsbuf, wob,
                                       A_bf, X_bf, Wq_bf, Wk_bf, fcw_bf, pw_bf, WOt_bf);
    gemm_qk<<<dim3(30, 16), 256, 0, stream>>>(A_bf, Wq_bf, Wq_b, qbuf,
                                              X_bf, Wk_bf, Wk_b, kbbuf, kvb);
    transform_qk<<<3072, 256, 0, stream>>>(qbuf, kbbuf, Sbuf, rcbuf, rsbuf,
                                           q_hi, q_lo, kf_hi, kf_lo);
    attn_scores<<<7680, 64, 0, stream>>>(q_hi, q_lo, kf_hi, kf_lo, pZ, pP);
    mlp_fused<<<1536, 256, 0, stream>>>(pP, pZ, sink, kvb,
                                        fcw_bf, fc_b, pw_bf, proj_b, v_nulls, ctx_bf);
    gemm_wo_splitk<<<dim3(12, 32, 4), 256, 0, stream>>>(ctx_bf, WOt_bf, wop);
    wo_reduce<<<1536, 256, 0, stream>>>(wop, wob, out);
}

// Round 14
// 246.174 us; speedup vs baseline: 1.4252x; 1.1827x over previous
//
#include <hip/hip_runtime.h>
#include <math.h>

#define B_   2
#define T_   1024
#define C_   768
#define DH_  64
#define NH_  12
#define HT_  48

typedef short bf16x8 __attribute__((ext_vector_type(8)));
typedef float f32x4 __attribute__((ext_vector_type(4)));

__device__ __forceinline__ float wave_sum(float v) {
#pragma unroll
    for (int off = 32; off; off >>= 1) v += __shfl_xor(v, off, 64);
    return v;
}
__device__ __forceinline__ unsigned short rne_bf16(float f) {
    unsigned u = __float_as_uint(f);
    return (unsigned short)((u + 0x7FFFu + ((u >> 16) & 1u)) >> 16);
}
__device__ __forceinline__ float bf2f(unsigned short u) {
    return __uint_as_float((unsigned)u << 16);
}

#define LOG2E 1.4426950408889634f
#define KBIAS 32.0f

// work tables: 40 (tile,part) units per (b,h), heavy-first. chunk = 64 cols, part = 4 chunks.
__constant__ int c_tileTab[40] = {15,15,15,15, 14,14,14, 13,13,13, 12,12,12, 11,11,11,
                                  10,10, 9,9, 8,8, 7,7, 6, 5, 4, 3,
                                  14,10,6,2, 13,9,5,1, 12,8,4,0};
__constant__ int c_partTab[40] = { 0, 1, 2, 3,  0, 1, 2,  0, 1, 2,  0, 1, 2,  0, 1, 2,
                                   0, 1, 0,1, 0,1, 0,1, 0, 0, 0, 0,
                                   3, 2,1,0,  3,2,1,0,  3,2,1,0};

// ---------------------------------------------------------------- fused prep: wo_transpose + cvt + St/rope/wob
// St[h][c][d] = (I + S_h)[d][e(c)] bf16 hi/lo, with rope-paired column perm:
//   c = j*16+i  ->  e = (j&1) + 2*(((j>>1)<<4) + i)
// so the MFMA output lane (holding cols {i,16+i,32+i,48+i}) owns rope pairs locally.
__global__ __launch_bounds__(256) void prep_all(
    const float* __restrict__ wA, const float* __restrict__ wb, const float* __restrict__ WOb,
    const float* __restrict__ A, const float* __restrict__ X,
    const float* __restrict__ Wq, const float* __restrict__ Wk,
    const float* __restrict__ fcw, const float* __restrict__ pw, const float* __restrict__ WO,
    unsigned short* __restrict__ sthi, unsigned short* __restrict__ stlo,
    float* __restrict__ rc, float* __restrict__ rs, float* __restrict__ wob,
    unsigned short* __restrict__ Ab, unsigned short* __restrict__ Xb,
    unsigned short* __restrict__ Wqb, unsigned short* __restrict__ Wkb,
    unsigned short* __restrict__ fcb, unsigned short* __restrict__ pwb,
    unsigned short* __restrict__ WOt) {
    __shared__ float tl[32][33];
    const int bid = blockIdx.x;
    if (bid < 2304) {               // WO transpose (4,768,768) -> WOt[d][n*768+c] bf16
        const int n = bid / 576, rem = bid % 576;
        const int d0 = (rem / 24) * 32, c0 = (rem % 24) * 32;
        const int tx = threadIdx.x & 31, ty = threadIdx.x >> 5;
#pragma unroll
        for (int p = 0; p < 4; p++)
            tl[ty + p * 8][tx] = WO[(size_t)n * 589824 + (size_t)(c0 + ty + p * 8) * 768 + d0 + tx];
        __syncthreads();
#pragma unroll
        for (int p = 0; p < 4; p++)
            WOt[(size_t)(d0 + ty + p * 8) * 3072 + n * 768 + c0 + tx] = rne_bf16(tl[tx][ty + p * 8]);
    } else if (bid < 8288) {        // f32 -> bf16 conversions, float4 granularity
        int i = (bid - 2304) * 256 + threadIdx.x;
        const float* s; unsigned short* d; int o;
        if (i < 393216)       { s = A;   d = Ab;  o = i; }
        else if (i < 786432)  { s = X;   d = Xb;  o = i - 393216; }
        else if (i < 1376256) { s = Wq;  d = Wqb; o = i - 786432; }
        else if (i < 1523712) { s = Wk;  d = Wkb; o = i - 1376256; }
        else if (i < 1527808) { s = fcw; d = fcb; o = i - 1523712; }
        else if (i < 1531904) { s = pw;  d = pwb; o = i - 1527808; }
        else return;
        float4 v = reinterpret_cast<const float4*>(s)[o];
        ushort4 u;
        u.x = rne_bf16(v.x); u.y = rne_bf16(v.y); u.z = rne_bf16(v.z); u.w = rne_bf16(v.w);
        reinterpret_cast<ushort4*>(d)[o] = u;
    } else {                        // St (hi/lo), rope tables, wob
        int i = (bid - 8288) * 256 + threadIdx.x;
        if (i < HT_ * 64 * 64) {
            int d = i & 63, c = (i >> 6) & 63, h2 = i >> 12;
            int j = c >> 4, i15 = c & 15;
            int e = (j & 1) + 2 * (((j >> 1) << 4) + i15);
            float v = wA[d * 64 + e] - wA[e * 64 + d];
            if (d == e) v += 1.f + wb[h2 * 64 + e];
            unsigned short hi = rne_bf16(v);
            sthi[i] = hi;
            stlo[i] = rne_bf16(v - bf2f(hi));
        } else if (i < HT_ * 64 * 64 + T_ * 32) {
            int j = i - HT_ * 64 * 64;
            int t = j >> 5, f = j & 31;
            float invf = (float)(1.0 / pow(10000.0, (double)f / 32.0));
            float fr = (float)t * invf;
            rc[j] = cosf(fr);
            rs[j] = sinf(fr);
        } else if (i < HT_ * 64 * 64 + T_ * 32 + C_) {
            int d = i - (HT_ * 64 * 64 + T_ * 32);
            wob[d] = WOb[d] + WOb[C_ + d] + WOb[2 * C_ + d] + WOb[3 * C_ + d];
        }
    }
}

// ---------------------------------------------------------------- q-proj + k-proj in one grid (128x128 MFMA, K=768)
// k-branch also emits vanilla-k bf16 copy kvb in (b,hk,t,64) layout.
__global__ __launch_bounds__(256) void gemm_qk(
    const unsigned short* __restrict__ Aq, const unsigned short* __restrict__ Wqw,
    const float* __restrict__ bq, float* __restrict__ Cq,
    const unsigned short* __restrict__ Ak, const unsigned short* __restrict__ Wkw,
    const float* __restrict__ bk, float* __restrict__ Ck,
    unsigned short* __restrict__ kvb) {
    __shared__ unsigned short Asd[128][40];
    __shared__ unsigned short Bsd[128][40];
    int bx = blockIdx.x;
    const bool isK = (bx >= 24);
    const unsigned short *A, *W; const float* bias; float* C; int N;
    if (!isK) { A = Aq; W = Wqw; bias = bq; C = Cq; N = 3072; }
    else { bx -= 24; A = Ak; W = Wkw; bias = bk; C = Ck; N = 768; }
    const int K = 768;
    const int tid = threadIdx.x;
    const int wv = tid >> 6, lane = tid & 63;
    const int m0 = blockIdx.y * 128, n0 = bx * 128;
    const int wr = (wv >> 1) * 64, wc = (wv & 1) * 64;
    const int l15 = lane & 15, l4 = lane >> 4;
    const int srow = tid >> 2, soff = (tid & 3) * 8;
    f32x4 acc[4][4] = {};
    for (int k0 = 0; k0 < K; k0 += 32) {
        uint4 a0 = *reinterpret_cast<const uint4*>(A + (size_t)(m0 + srow) * K + k0 + soff);
        uint4 a1 = *reinterpret_cast<const uint4*>(A + (size_t)(m0 + srow + 64) * K + k0 + soff);
        uint4 b0 = *reinterpret_cast<const uint4*>(W + (size_t)(n0 + srow) * K + k0 + soff);
        uint4 b1 = *reinterpret_cast<const uint4*>(W + (size_t)(n0 + srow + 64) * K + k0 + soff);
        *reinterpret_cast<uint4*>(&Asd[srow][soff])      = a0;
        *reinterpret_cast<uint4*>(&Asd[srow + 64][soff]) = a1;
        *reinterpret_cast<uint4*>(&Bsd[srow][soff])      = b0;
        *reinterpret_cast<uint4*>(&Bsd[srow + 64][soff]) = b1;
        __syncthreads();
        bf16x8 af[4], bfr[4];
#pragma unroll
        for (int i = 0; i < 4; i++)
            af[i] = *reinterpret_cast<const bf16x8*>(&Asd[wr + i * 16 + l15][l4 * 8]);
#pragma unroll
        for (int j = 0; j < 4; j++)
            bfr[j] = *reinterpret_cast<const bf16x8*>(&Bsd[wc + j * 16 + l15][l4 * 8]);
#pragma unroll
        for (int i = 0; i < 4; i++)
#pragma unroll
            for (int j = 0; j < 4; j++)
                acc[i][j] = __builtin_amdgcn_mfma_f32_16x16x32_bf16(af[i], bfr[j], acc[i][j], 0, 0, 0);
        __syncthreads();
    }
#pragma unroll
    for (int i = 0; i < 4; i++)
#pragma unroll
        for (int j = 0; j < 4; j++) {
            int col = n0 + wc + j * 16 + l15;
            float bv = bias[col];
#pragma unroll
            for (int r = 0; r < 4; r++) {
                int row = m0 + wr + i * 16 + l4 * 4 + r;
                float o = acc[i][j][r] + bv;
                C[(size_t)row * N + col] = o;
                if (isK) {
                    int hk2 = col >> 6, d2 = col & 63;
                    int bb = row >> 10, tt = row & 1023;
                    kvb[((((size_t)(bb * 12 + hk2)) << 10) + tt) * 64 + d2] = rne_bf16(o);
                }
            }
        }
}

// ---------------------------------------------------------------- WO GEMM split-K=4: partials (no bias/scale)
__global__ __launch_bounds__(256) void gemm_wo_splitk(const unsigned short* __restrict__ A,
                                                      const unsigned short* __restrict__ W,
                                                      float* __restrict__ Cp) {
    __shared__ unsigned short Asd[64][40];
    __shared__ unsigned short Bsd[64][40];
    const int tid = threadIdx.x;
    const int wv = tid >> 6, lane = tid & 63;
    const int m0 = blockIdx.y * 64, n0 = blockIdx.x * 64, z = blockIdx.z;
    const int l15 = lane & 15, l4 = lane >> 4;
    const int srow = tid >> 2, soff = (tid & 3) * 8;
    const int K = 3072;
    float* C = Cp + (size_t)z * 1572864;
    f32x4 acc[4] = {};
    for (int k0 = z * 768; k0 < z * 768 + 768; k0 += 32) {
        uint4 a0 = *reinterpret_cast<const uint4*>(A + (size_t)(m0 + srow) * K + k0 + soff);
        uint4 b0 = *reinterpret_cast<const uint4*>(W + (size_t)(n0 + srow) * K + k0 + soff);
        *reinterpret_cast<uint4*>(&Asd[srow][soff]) = a0;
        *reinterpret_cast<uint4*>(&Bsd[srow][soff]) = b0;
        __syncthreads();
        bf16x8 af = *reinterpret_cast<const bf16x8*>(&Asd[wv * 16 + l15][l4 * 8]);
#pragma unroll
        for (int j = 0; j < 4; j++) {
            bf16x8 bfr = *reinterpret_cast<const bf16x8*>(&Bsd[j * 16 + l15][l4 * 8]);
            acc[j] = __builtin_amdgcn_mfma_f32_16x16x32_bf16(af, bfr, acc[j], 0, 0, 0);
        }
        __syncthreads();
    }
#pragma unroll
    for (int j = 0; j < 4; j++) {
        int col = n0 + j * 16 + l15;
#pragma unroll
        for (int r = 0; r < 4; r++) {
            int row = m0 + wv * 16 + l4 * 4 + r;
            C[(size_t)row * 768 + col] = acc[j][r];
        }
    }
}

// ---------------------------------------------------------------- WO reduce: out = (p0+p1+p2+p3 + wob) * 0.25
__global__ __launch_bounds__(256) void wo_reduce(const float* __restrict__ Cp,
                                                 const float* __restrict__ wob,
                                                 float* __restrict__ out) {
    int i = blockIdx.x * 256 + threadIdx.x;   // float4 index, 393216 total
    const float4* p0 = reinterpret_cast<const float4*>(Cp);
    const float4* p1 = reinterpret_cast<const float4*>(Cp + 1572864);
    const float4* p2 = reinterpret_cast<const float4*>(Cp + 3145728);
    const float4* p3 = reinterpret_cast<const float4*>(Cp + 4718592);
    float4 a = p0[i], b = p1[i], c = p2[i], d = p3[i];
    float4 w = reinterpret_cast<const float4*>(wob)[i % 192];
    float4 o;
    o.x = (a.x + b.x + c.x + d.x + w.x) * 0.25f;
    o.y = (a.y + b.y + c.y + d.y + w.y) * 0.25f;
    o.z = (a.z + b.z + c.z + d.z + w.z) * 0.25f;
    o.w = (a.w + b.w + c.w + d.w + w.w) * 0.25f;
    reinterpret_cast<float4*>(out)[i] = o;
}

// ---------------------------------------------------------------- MFMA q+k transform: rmsnorm(q) -> x@(I+S) -> rope -> bf16 hi/lo
// one wave per 16 rows of one head. A = rows (lane l15 = row, l4*8 = k-dims),
// B = St_h (rope-paired cols). Output lane holds cols {i,16+i,32+i,48+i} =
// rope pairs (x1,x2) locally for rows l4*4+r. No LDS.
__global__ __launch_bounds__(256) void transform_qk2(
    const float* __restrict__ qb, const float* __restrict__ kbv,
    const unsigned short* __restrict__ sthi, const unsigned short* __restrict__ stlo,
    const float* __restrict__ rc, const float* __restrict__ rs,
    unsigned short* __restrict__ qhi, unsigned short* __restrict__ qlo,
    unsigned short* __restrict__ khi, unsigned short* __restrict__ klo) {
    const int tid = threadIdx.x, wv = tid >> 6, lane = tid & 63;
    const int l15 = lane & 15, l4 = lane >> 4;
    const int wid = blockIdx.x * 4 + wv;          // 0..12287
    const bool isQ = wid < 6144;
    const int widl = isQ ? wid : wid - 6144;
    const int h = widl >> 7;                      // 0..47
    const int rbase = (widl & 127) << 4;          // row group base in [0,2048)
    const int hk = h % 12;

    // ---- load A-frag: row rbase+l15, dims [l4*8,+8) and [32+l4*8,+8) ----
    bf16x8 ah[2], al[2];
    {
        int rg = rbase + l15;
        int b = rg >> 10, t = rg & 1023;
        const float* src = isQ
            ? qb + ((((size_t)(b << 10) + t) * 48 + h) << 6)
            : kbv + ((((size_t)(b << 10) + t) * 12 + hk) << 6);
        float4 f0 = *reinterpret_cast<const float4*>(src + l4 * 8);
        float4 f1 = *reinterpret_cast<const float4*>(src + l4 * 8 + 4);
        float4 f2 = *reinterpret_cast<const float4*>(src + 32 + l4 * 8);
        float4 f3 = *reinterpret_cast<const float4*>(src + 32 + l4 * 8 + 4);
        if (isQ) {
            float ss = f0.x*f0.x + f0.y*f0.y + f0.z*f0.z + f0.w*f0.w
                     + f1.x*f1.x + f1.y*f1.y + f1.z*f1.z + f1.w*f1.w
                     + f2.x*f2.x + f2.y*f2.y + f2.z*f2.z + f2.w*f2.w
                     + f3.x*f3.x + f3.y*f3.y + f3.z*f3.z + f3.w*f3.w;
            ss += __shfl_xor(ss, 16, 64);
            ss += __shfl_xor(ss, 32, 64);
            float sc = 1.f / sqrtf(ss * (1.f / 64.f) + 1.1920928955078125e-07f);
            f0.x *= sc; f0.y *= sc; f0.z *= sc; f0.w *= sc;
            f1.x *= sc; f1.y *= sc; f1.z *= sc; f1.w *= sc;
            f2.x *= sc; f2.y *= sc; f2.z *= sc; f2.w *= sc;
            f3.x *= sc; f3.y *= sc; f3.z *= sc; f3.w *= sc;
        }
        float v0[8] = {f0.x, f0.y, f0.z, f0.w, f1.x, f1.y, f1.z, f1.w};
        float v1[8] = {f2.x, f2.y, f2.z, f2.w, f3.x, f3.y, f3.z, f3.w};
#pragma unroll
        for (int e = 0; e < 8; e++) {
            unsigned short h0 = rne_bf16(v0[e]);
            ah[0][e] = (short)h0; al[0][e] = (short)rne_bf16(v0[e] - bf2f(h0));
            unsigned short h1 = rne_bf16(v1[e]);
            ah[1][e] = (short)h1; al[1][e] = (short)rne_bf16(v1[e] - bf2f(h1));
        }
    }

    // ---- MFMA with St_h (hi/lo, 3-product) ----
    const unsigned short* sh_ = sthi + (h << 12);
    const unsigned short* sl_ = stlo + (h << 12);
    f32x4 acc[4] = {};
#pragma unroll
    for (int ks = 0; ks < 2; ks++)
#pragma unroll
        for (int j = 0; j < 4; j++) {
            bf16x8 bh = *reinterpret_cast<const bf16x8*>(sh_ + (j * 16 + l15) * 64 + ks * 32 + l4 * 8);
            bf16x8 bl = *reinterpret_cast<const bf16x8*>(sl_ + (j * 16 + l15) * 64 + ks * 32 + l4 * 8);
            acc[j] = __builtin_amdgcn_mfma_f32_16x16x32_bf16(ah[ks], bh, acc[j], 0, 0, 0);
            acc[j] = __builtin_amdgcn_mfma_f32_16x16x32_bf16(al[ks], bh, acc[j], 0, 0, 0);
            acc[j] = __builtin_amdgcn_mfma_f32_16x16x32_bf16(ah[ks], bl, acc[j], 0, 0, 0);
        }

    // ---- rope + hi/lo split + store (lane-local pairs) ----
    unsigned short* ohi = isQ ? qhi : khi;
    unsigned short* olo = isQ ? qlo : klo;
    const float qscl = 0.125f * LOG2E;
#pragma unroll
    for (int r = 0; r < 4; r++) {
        int rg = rbase + l4 * 4 + r;
        int b = rg >> 10, t = rg & 1023;
        float c0 = rc[t * 32 + l15],      s0 = rs[t * 32 + l15];
        float c1 = rc[t * 32 + 16 + l15], s1 = rs[t * 32 + 16 + l15];
        float o0 = acc[0][r] * c0 - acc[1][r] * s0;   // out dim l15
        float o2 = acc[0][r] * s0 + acc[1][r] * c0;   // out dim 32+l15
        float o1 = acc[2][r] * c1 - acc[3][r] * s1;   // out dim 16+l15
        float o3 = acc[2][r] * s1 + acc[3][r] * c1;   // out dim 48+l15
        if (isQ) { o0 *= qscl; o1 *= qscl; o2 *= qscl; o3 *= qscl; }
        size_t obase = ((((size_t)(b * 48 + h)) << 10) + t) * 64;
        unsigned short h0 = rne_bf16(o0), h1 = rne_bf16(o1);
        unsigned short h2 = rne_bf16(o2), h3 = rne_bf16(o3);
        ohi[obase + l15]      = h0;  olo[obase + l15]      = rne_bf16(o0 - bf2f(h0));
        ohi[obase + 16 + l15] = h1;  olo[obase + 16 + l15] = rne_bf16(o1 - bf2f(h1));
        ohi[obase + 32 + l15] = h2;  olo[obase + 32 + l15] = rne_bf16(o2 - bf2f(h2));
        ohi[obase + 48 + l15] = h3;  olo[obase + 48 + l15] = rne_bf16(o3 - bf2f(h3));
    }
}

#define POPQ(qq)                                                                  \
    {                                                                             \
        bool tk = (qq[0] == hm);                                                  \
        qq[0]=tk?qq[1]:qq[0]; qq[1]=tk?qq[2]:qq[1]; qq[2]=tk?qq[3]:qq[2];         \
        qq[3]=tk?qq[4]:qq[3]; qq[4]=tk?qq[5]:qq[4]; qq[5]=tk?qq[6]:qq[5];         \
        qq[6]=tk?qq[7]:qq[6]; qq[7]=tk?qq[8]:qq[7]; qq[8]=tk?qq[9]:qq[8];         \
        qq[9]=tk?qq[10]:qq[9]; qq[10]=tk?qq[11]:qq[10]; qq[11]=tk?0u:qq[11];      \
    }

#define TOP12INS(pln, pk)                                                         \
    {                                                                             \
        unsigned _p = (pk);                                                       \
        _Pragma("unroll")                                                         \
        for (int jj = 0; jj < 12; jj++) {                                         \
            unsigned mx = pln[jj] > _p ? pln[jj] : _p;                            \
            _p = pln[jj] > _p ? _p : pln[jj];                                     \
            pln[jj] = mx;                                                         \
        }                                                                         \
    }

// ---------------------------------------------------------------- phase A: MFMA scores, exp2 domain, +KBIAS in acc
// r6-measured launch shape: ONE wave per 64-thread block, natural unit map
// (moderate occupancy keeps the concurrent k working set within L2; higher
// occupancy measured to thrash L2: FETCH 52->238->375MB r6/r8/r9).
__global__ __launch_bounds__(64, 3) void attn_scores(
    const unsigned short* __restrict__ qhi, const unsigned short* __restrict__ qlo,
    const unsigned short* __restrict__ khi, const unsigned short* __restrict__ klo,
    float* __restrict__ pZ, unsigned int* __restrict__ pP) {
    const int lane = threadIdx.x;
    const int bid = blockIdx.x;
    const int u = bid / 96, bh = bid % 96;
    const int tile = c_tileTab[u >> 1], part = c_partTab[u >> 1], half = u & 1;
    const int l15 = lane & 15, l4 = lane >> 4;
    const int t0 = (tile << 6) + (half << 5);
    const int c0 = part << 2;
    const int c1 = min(c0 + 4, tile + 1);
    const size_t base = ((size_t)bh) << 16;

    bf16x8 qh8[2][2], ql8[2][2];
#pragma unroll
    for (int ni = 0; ni < 2; ni++)
#pragma unroll
        for (int ks = 0; ks < 2; ks++) {
            size_t off = base + (size_t)(t0 + ni * 16 + l15) * 64 + ks * 32 + l4 * 8;
            qh8[ni][ks] = *reinterpret_cast<const bf16x8*>(qhi + off);
            ql8[ni][ks] = *reinterpret_cast<const bf16x8*>(qlo + off);
        }

    unsigned int pl[2][12];
#pragma unroll
    for (int ni = 0; ni < 2; ni++)
#pragma unroll
        for (int i = 0; i < 12; i++) pl[ni][i] = 0u;
    float Zp[2] = {0.f, 0.f};

    for (int cc = c0; cc < c1; ++cc) {
        f32x4 acc[4][2];
#pragma unroll
        for (int mi = 0; mi < 4; mi++)
#pragma unroll
            for (int ni = 0; ni < 2; ni++)
                acc[mi][ni] = (f32x4){KBIAS, KBIAS, KBIAS, KBIAS};
#pragma unroll
        for (int ks = 0; ks < 2; ks++) {
            bf16x8 kh8[4], kl8[4];
#pragma unroll
            for (int mi = 0; mi < 4; mi++) {
                size_t off = base + (size_t)((cc << 6) + mi * 16 + l15) * 64 + ks * 32 + l4 * 8;
                kh8[mi] = *reinterpret_cast<const bf16x8*>(khi + off);
                kl8[mi] = *reinterpret_cast<const bf16x8*>(klo + off);
            }
#pragma unroll
            for (int mi = 0; mi < 4; mi++)
#pragma unroll
                for (int ni = 0; ni < 2; ni++) {
                    acc[mi][ni] = __builtin_amdgcn_mfma_f32_16x16x32_bf16(kh8[mi], qh8[ni][ks], acc[mi][ni], 0, 0, 0);
                    acc[mi][ni] = __builtin_amdgcn_mfma_f32_16x16x32_bf16(kh8[mi], ql8[ni][ks], acc[mi][ni], 0, 0, 0);
                    acc[mi][ni] = __builtin_amdgcn_mfma_f32_16x16x32_bf16(kl8[mi], qh8[ni][ks], acc[mi][ni], 0, 0, 0);
                }
        }
        if (cc == tile) {   // diagonal chunk: causal mask
#pragma unroll
            for (int ni = 0; ni < 2; ni++) {
                const int tq = t0 + ni * 16 + l15;
#pragma unroll
                for (int mi = 0; mi < 4; mi++)
#pragma unroll
                    for (int r = 0; r < 4; r++) {
                        int kcol = (cc << 6) + mi * 16 + l4 * 4 + r;
                        float s = acc[mi][ni][r];
                        bool ok = kcol <= tq;
                        float e = exp2f(s);
                        Zp[ni] += ok ? e : 0.f;
                        unsigned pk = (__float_as_uint(s) & 0xFFFFFC00u) | (unsigned)(1023 - kcol);
                        pk = ok ? pk : 0u;
                        TOP12INS(pl[ni], pk);
                    }
            }
        } else {            // interior chunk: all valid
#pragma unroll
            for (int ni = 0; ni < 2; ni++) {
#pragma unroll
                for (int mi = 0; mi < 4; mi++)
#pragma unroll
                    for (int r = 0; r < 4; r++) {
                        int kcol = (cc << 6) + mi * 16 + l4 * 4 + r;
                        float s = acc[mi][ni][r];
                        Zp[ni] += exp2f(s);
                        unsigned pk = (__float_as_uint(s) & 0xFFFFFC00u) | (unsigned)(1023 - kcol);
                        TOP12INS(pl[ni], pk);
                    }
            }
        }
    }

    // in-wave 4-lane merge per qrow (single wave per block)
    __shared__ unsigned int lsh[64][2][12];
    __shared__ float zsh[64][2];
#pragma unroll
    for (int ni = 0; ni < 2; ni++) {
#pragma unroll
        for (int i = 0; i < 12; i++) lsh[lane][ni][i] = pl[ni][i];
        zsh[lane][ni] = Zp[ni];
    }
    __syncthreads();
    if (lane < 32) {
        const int ni = lane >> 4, c = lane & 15;
        unsigned int m0[12], m1[12], m2[12], m3[12];
#pragma unroll
        for (int i = 0; i < 12; i++) {
            m0[i] = lsh[c][ni][i];
            m1[i] = lsh[c + 16][ni][i];
            m2[i] = lsh[c + 32][ni][i];
            m3[i] = lsh[c + 48][ni][i];
        }
        float Z = zsh[c][ni] + zsh[c + 16][ni] + zsh[c + 32][ni] + zsh[c + 48][ni];
        unsigned int out[12];
#pragma unroll
        for (int rd = 0; rd < 12; rd++) {
            unsigned int ha = m0[0] > m1[0] ? m0[0] : m1[0];
            unsigned int hb2 = m2[0] > m3[0] ? m2[0] : m3[0];
            unsigned int hm = ha > hb2 ? ha : hb2;
            POPQ(m0); POPQ(m1); POPQ(m2); POPQ(m3);
            out[rd] = hm;
        }
        const size_t r = (((size_t)bh) << 10) + t0 + lane;
        pZ[r * 4 + part] = Z;
        unsigned int* pp = pP + r * 48 + part * 12;
        *reinterpret_cast<uint4*>(pp + 0) = make_uint4(out[0], out[1], out[2], out[3]);
        *reinterpret_cast<uint4*>(pp + 4) = make_uint4(out[4], out[5], out[6], out[7]);
        *reinterpret_cast<uint4*>(pp + 8) = make_uint4(out[8], out[9], out[10], out[11]);
    }
}

// ---------------------------------------------------------------- fused merge + COALESCED gather + fc + act + proj
// 256 threads / 4 waves. Per wave: 16 rows.
// Merge: lane l15 = row, l4 = part queue; (idx,w) published to LDS.
// Gather: lane (g=l4, i=l15): group g reads ONE bf16 k-row per instr, lane i
// holds dims [4i,4i+4) -> 1 cache line per row, 4 lines/instr.
__global__ __launch_bounds__(256, 2) void mlp_fused(
    const unsigned int* __restrict__ pP, const float* __restrict__ pZ,
    const float* __restrict__ sink_s, const unsigned short* __restrict__ kvb,
    const unsigned short* __restrict__ fcw, const float* __restrict__ fcb,
    const unsigned short* __restrict__ pw, const float* __restrict__ pb,
    const float* __restrict__ vn, unsigned short* __restrict__ ctx) {
    const int tid = threadIdx.x, wv = tid >> 6, lane = tid & 63;
    const int l15 = lane & 15, l4 = lane >> 4;
    const int wid = blockIdx.x * 4 + wv;          // 0..6143
    const int r0 = wid << 4;
    const int bh = wid >> 6;
    const int h = bh % 48, b = bh / 48, hk = h % 12;
    const int tbase = r0 & 1023;
    const int tile = tbase >> 6;
    const int npart = (tile >> 2) + 1;            // wave-uniform
    __shared__ __align__(16) char scratch[4][8704];  // phase D: f32[16][68]; phase E: u16[16][272]
    __shared__ unsigned int idwi[4][16][12];
    __shared__ float idww[4][16][12];

    // ---- phase A: part-merge; publish (idx,w) to LDS ----
    const int row = r0 + l15;
    unsigned int qq[12];
    {
        const bool val = l4 < npart;
        uint4 x0 = make_uint4(0,0,0,0), x1 = x0, x2 = x0;
        if (val) {
            const uint4* ip = reinterpret_cast<const uint4*>(pP + (size_t)row * 48 + l4 * 12);
            x0 = ip[0]; x1 = ip[1]; x2 = ip[2];
        }
        qq[0]=x0.x; qq[1]=x0.y; qq[2]=x0.z; qq[3]=x0.w;
        qq[4]=x1.x; qq[5]=x1.y; qq[6]=x1.z; qq[7]=x1.w;
        qq[8]=x2.x; qq[9]=x2.y; qq[10]=x2.z; qq[11]=x2.w;
    }
    float Zl = (l4 < npart) ? pZ[(size_t)row * 4 + l4] : 0.f;
    float Z = Zl;
    Z += __shfl_xor(Z, 16, 64);
    Z += __shfl_xor(Z, 32, 64);
    const float es = exp2f(sink_s[h] * LOG2E + KBIAS);
    const float invZ = 1.f / (Z + es);
    const float psink = es * invZ;                // for row l15

#pragma unroll
    for (int rd = 0; rd < 12; rd++) {
        unsigned int m = qq[0];
        unsigned int o1 = __shfl_xor(m, 16, 64); m = m > o1 ? m : o1;
        unsigned int o2 = __shfl_xor(m, 32, 64); m = m > o2 ? m : o2;
        const unsigned int hm = m;                // uniform in 4-lane group
        POPQ(qq);
        if (l4 == 0) {
            idwi[wv][l15][rd] = 1023u - (hm & 1023u);
            idww[wv][l15][rd] = (hm == 0u) ? 0.f : exp2f(__uint_as_float(hm & 0xFFFFFC00u)) * invZ;
        }
    }
    __syncthreads();

    // ---- phase C: coalesced gather from bf16 kvb ----
    const unsigned short* kvroot = kvb + (((size_t)(b * 12 + hk)) << 16);
    float acc4[4][4];
#pragma unroll
    for (int i = 0; i < 4; i++)
#pragma unroll
        for (int e = 0; e < 4; e++) acc4[i][e] = 0.f;
#pragma unroll
    for (int rsub = 0; rsub < 4; rsub++) {
        const int grow = rsub * 4 + l4;           // row 0..15 handled by this group
#pragma unroll
        for (int rr = 0; rr < 12; rr++) {
            unsigned idx = idwi[wv][grow][rr];
            float w = idww[wv][grow][rr];
            ushort4 kv = *reinterpret_cast<const ushort4*>(kvroot + ((size_t)idx << 6) + l15 * 4);
            acc4[rsub][0] = fmaf(w, bf2f(kv.x), acc4[rsub][0]);
            acc4[rsub][1] = fmaf(w, bf2f(kv.y), acc4[rsub][1]);
            acc4[rsub][2] = fmaf(w, bf2f(kv.z), acc4[rsub][2]);
            acc4[rsub][3] = fmaf(w, bf2f(kv.w), acc4[rsub][3]);
        }
        ushort4 kv = *reinterpret_cast<const ushort4*>(kvroot + ((size_t)(tbase + grow) << 6) + l15 * 4);
        acc4[rsub][0] = (acc4[rsub][0] + bf2f(kv.x)) * (1.f / 13.f);
        acc4[rsub][1] = (acc4[rsub][1] + bf2f(kv.y)) * (1.f / 13.f);
        acc4[rsub][2] = (acc4[rsub][2] + bf2f(kv.z)) * (1.f / 13.f);
        acc4[rsub][3] = (acc4[rsub][3] + bf2f(kv.w)) * (1.f / 13.f);
    }

    // ---- phase D: transpose to MFMA layout via per-wave LDS ----
    float* mkls = reinterpret_cast<float*>(scratch[wv]);   // [16][68]
#pragma unroll
    for (int rsub = 0; rsub < 4; rsub++)
        *reinterpret_cast<float4*>(&mkls[(rsub * 4 + l4) * 68 + l15 * 4]) =
            make_float4(acc4[rsub][0], acc4[rsub][1], acc4[rsub][2], acc4[rsub][3]);
    __syncthreads();
    bf16x8 amk[2];
#pragma unroll
    for (int ks = 0; ks < 2; ks++) {
        float4 f0 = *reinterpret_cast<const float4*>(&mkls[l15 * 68 + ks * 32 + l4 * 8]);
        float4 f1 = *reinterpret_cast<const float4*>(&mkls[l15 * 68 + ks * 32 + l4 * 8 + 4]);
        amk[ks][0] = (short)rne_bf16(f0.x); amk[ks][1] = (short)rne_bf16(f0.y);
        amk[ks][2] = (short)rne_bf16(f0.z); amk[ks][3] = (short)rne_bf16(f0.w);
        amk[ks][4] = (short)rne_bf16(f1.x); amk[ks][5] = (short)rne_bf16(f1.y);
        amk[ks][6] = (short)rne_bf16(f1.z); amk[ks][7] = (short)rne_bf16(f1.w);
    }
    __syncthreads();

    // ---- fc: 16 rows x 256 cols, K=64 ----
    f32x4 hacc[16] = {};
#pragma unroll
    for (int ks = 0; ks < 2; ks++)
#pragma unroll
        for (int j = 0; j < 16; j++) {
            bf16x8 bw = *reinterpret_cast<const bf16x8*>(fcw + (j * 16 + l15) * 64 + ks * 32 + l4 * 8);
            hacc[j] = __builtin_amdgcn_mfma_f32_16x16x32_bf16(amk[ks], bw, hacc[j], 0, 0, 0);
        }

    // bias + activation + rmsnorm(256) + gate  (row = l4*4+r, col = j*16+l15)
    float ss[4] = {0.f, 0.f, 0.f, 0.f};
#pragma unroll
    for (int j = 0; j < 16; j++) {
        float bv = fcb[j * 16 + l15];
#pragma unroll
        for (int r = 0; r < 4; r++) {
            float x = hacc[j][r] + bv;
            float y = x * x + 0.75f * x * x * x;
            hacc[j][r] = y;
            ss[r] = fmaf(y, y, ss[r]);
        }
    }
#pragma unroll
    for (int m = 1; m < 16; m <<= 1)
#pragma unroll
        for (int r = 0; r < 4; r++) ss[r] += __shfl_xor(ss[r], m, 64);
    float rinv[4];
#pragma unroll
    for (int r = 0; r < 4; r++)
        rinv[r] = 1.f / sqrtf(ss[r] * (1.f / 256.f) + 1.1920928955078125e-07f);
    unsigned short (*hsd)[272] = reinterpret_cast<unsigned short (*)[272]>(scratch[wv]);
#pragma unroll
    for (int j = 0; j < 16; j++)
#pragma unroll
        for (int r = 0; r < 4; r++) {
            float z = hacc[j][r] * rinv[r];
            float g = z / (1.f + exp2f(-2.616571036720458f * z));   // MLP_SCALE*log2e
            hsd[l4 * 4 + r][j * 16 + l15] = rne_bf16(g);
        }
    __syncthreads();

    // ---- proj: 16 rows x 64 cols, K=256 ----
    f32x4 oacc[4] = {};
#pragma unroll
    for (int ks = 0; ks < 8; ks++) {
        bf16x8 ah = *reinterpret_cast<const bf16x8*>(&hsd[l15][ks * 32 + l4 * 8]);
#pragma unroll
        for (int j = 0; j < 4; j++) {
            bf16x8 bw = *reinterpret_cast<const bf16x8*>(pw + (j * 16 + l15) * 256 + ks * 32 + l4 * 8);
            oacc[j] = __builtin_amdgcn_mfma_f32_16x16x32_bf16(ah, bw, oacc[j], 0, 0, 0);
        }
    }
#pragma unroll
    for (int j = 0; j < 4; j++) {
        int d = j * 16 + l15;
        float pbv = pb[d];
        float vnv = vn[h * 64 + d];
#pragma unroll
        for (int r = 0; r < 4; r++) {
            int rloc = l4 * 4 + r;
            int t = tbase + rloc;
            float p = __shfl(psink, rloc, 64);    // psink of output row rloc
            float o = oacc[j][r] + pbv + p * vnv;
            ctx[((((size_t)(b << 10) + t) * 48 + h) << 6) + d] = rne_bf16(o);
        }
    }
}

// ---------------------------------------------------------------- launch
extern "C" void kernel_launch(void* const* d_in, const int* in_sizes, int n_in,
                              void* d_out, int out_size, void* d_ws, size_t ws_size,
                              hipStream_t stream) {
    (void)in_sizes; (void)n_in; (void)out_size; (void)ws_size;
    const float* A       = (const float*)d_in[0];
    const float* X       = (const float*)d_in[1];
    const float* Wq_w    = (const float*)d_in[2];
    const float* Wq_b    = (const float*)d_in[3];
    const float* Wk_w    = (const float*)d_in[4];
    const float* Wk_b    = (const float*)d_in[5];
    const float* wedge_A = (const float*)d_in[6];
    const float* wedge_b = (const float*)d_in[7];
    const float* sink    = (const float*)d_in[8];
    const float* v_nulls = (const float*)d_in[9];
    const float* fc_w    = (const float*)d_in[10];
    const float* fc_b    = (const float*)d_in[11];
    const float* proj_w  = (const float*)d_in[12];
    const float* proj_b  = (const float*)d_in[13];
    const float* WO      = (const float*)d_in[14];
    const float* WO_b    = (const float*)d_in[15];
    float* out = (float*)d_out;
    float* ws  = (float*)d_ws;

    // ---- workspace layout (float offsets) ----
    float*          qbuf   = ws;                                  // [0, 6291456) f32; later ctx_bf
    unsigned short* ctx_bf = (unsigned short*)ws;                 //   2048x3072 bf16
    float*          kbbuf  = ws + 6291456;                        // [6291456, 7864320) f32
    unsigned short* q_hi   = (unsigned short*)(ws + 7864320);     // [7864320, 11010048)
    float*          wop    = ws + 7864320;                        //   WO split-K partials (4x1572864), overlays q/k bf16
    unsigned short* q_lo   = (unsigned short*)(ws + 11010048);    // [11010048, 14155776)
    unsigned short* kf_hi  = (unsigned short*)(ws + 14155776);    // [14155776, 17301504)
    unsigned short* kf_lo  = (unsigned short*)(ws + 17301504);    // [17301504, 20447232)
    // region [20447232, 25559040): early = cvt scratch; late = pZ + pP
    unsigned short* A_bf   = (unsigned short*)(ws + 20447232);
    unsigned short* X_bf   = (unsigned short*)(ws + 21233664);
    unsigned short* Wq_bf  = (unsigned short*)(ws + 22020096);
    unsigned short* Wk_bf  = (unsigned short*)(ws + 23199744);
    unsigned short* Sthi   = (unsigned short*)(ws + 23494656);    // 196608 u16
    unsigned short* Stlo   = (unsigned short*)(ws + 23592960);    // 196608 u16, ends 23691264
    float*          rcbuf  = ws + 23691264;
    float*          rsbuf  = ws + 23724032;
    float*          pZ     = ws + 20447232;                       // 393216 f32
    unsigned int*   pP     = (unsigned int*)(ws + 20840448);      // 4718592 u32, ends 25559040
    // tail
    float*          wob    = ws + 25559040;
    unsigned short* fcw_bf = (unsigned short*)(ws + 25560064);
    unsigned short* pw_bf  = (unsigned short*)(ws + 25568256);
    unsigned short* WOt_bf = (unsigned short*)(ws + 25576448);    // ends 26756096
    unsigned short* kvb    = (unsigned short*)(ws + 26756096);    // 1572864 u16 -> ends 27542528 (110MB)

    prep_all<<<9187, 256, 0, stream>>>(wedge_A, wedge_b, WO_b,
                                       A, X, Wq_w, Wk_w, fc_w, proj_w, WO,
                                       Sthi, Stlo, rcbuf, rsbuf, wob,
                                       A_bf, X_bf, Wq_bf, Wk_bf, fcw_bf, pw_bf, WOt_bf);
    gemm_qk<<<dim3(30, 16), 256, 0, stream>>>(A_bf, Wq_bf, Wq_b, qbuf,
                                              X_bf, Wk_bf, Wk_b, kbbuf, kvb);
    transform_qk2<<<3072, 256, 0, stream>>>(qbuf, kbbuf, Sthi, Stlo, rcbuf, rsbuf,
                                            q_hi, q_lo, kf_hi, kf_lo);
    attn_scores<<<7680, 64, 0, stream>>>(q_hi, q_lo, kf_hi, kf_lo, pZ, pP);
    mlp_fused<<<1536, 256, 0, stream>>>(pP, pZ, sink, kvb,
                                        fcw_bf, fc_b, pw_bf, proj_b, v_nulls, ctx_bf);
    gemm_wo_splitk<<<dim3(12, 32, 4), 256, 0, stream>>>(ctx_bf, WOt_bf, wop);
    wo_reduce<<<1536, 256, 0, stream>>>(wop, wob, out);
}